// Round 1
// baseline (3831.778 us; speedup 1.0000x reference)
//
#include <hip/hip_runtime.h>
#include <math.h>

#define NF 8
#define HID 128
#define NGEO 15
#define NAPP 32
#define NCIN 50      // 3 + 15 + 32
#define BPF 256      // blocks per field in k_main
#define PPI 16       // points per block-iteration (4 waves x 4 points)

// ws int layout: [0..7] counts, [8..15] starts, [16..23] cursors, [32..] perm[N]

__device__ __forceinline__ void wave_fence() {
    asm volatile("s_waitcnt lgkmcnt(0)" ::: "memory");
}

__device__ __forceinline__ int assign_field(float px, float py, float pz,
                                            const float* __restrict__ cen) {
    int best = 0;
    float bd = 3.4e38f;
#pragma unroll
    for (int k = 0; k < NF; ++k) {
        float dx = px - cen[k * 3 + 0];
        float dy = py - cen[k * 3 + 1];
        float dz = pz - cen[k * 3 + 2];
        float d = fmaf(dx, dx, fmaf(dy, dy, dz * dz));
        if (d < bd) { bd = d; best = k; }
    }
    return best;
}

__global__ void k_count(const float* __restrict__ pos, const float* __restrict__ cen,
                        int n, int* __restrict__ ws) {
    int i = blockIdx.x * blockDim.x + threadIdx.x;
    int lane = threadIdx.x & 63;
    int f = -1;
    if (i < n) f = assign_field(pos[3 * i], pos[3 * i + 1], pos[3 * i + 2], cen);
#pragma unroll
    for (int k = 0; k < NF; ++k) {
        unsigned long long m = __ballot(f == k);
        if (m != 0ull && lane == __builtin_ctzll(m))
            atomicAdd(&ws[k], __builtin_popcountll(m));
    }
}

__global__ void k_scan(int* __restrict__ ws) {
    if (threadIdx.x == 0 && blockIdx.x == 0) {
        int s = 0;
        for (int k = 0; k < NF; ++k) {
            int c = ws[k];
            ws[8 + k] = s;   // starts
            ws[16 + k] = s;  // cursors
            s += c;
        }
    }
}

__global__ void k_scatter(const float* __restrict__ pos, const float* __restrict__ cen,
                          int n, int* __restrict__ ws) {
    int i = blockIdx.x * blockDim.x + threadIdx.x;
    int lane = threadIdx.x & 63;
    int f = -1;
    if (i < n) f = assign_field(pos[3 * i], pos[3 * i + 1], pos[3 * i + 2], cen);
    int* cursors = ws + 16;
    int* perm = ws + 32;
#pragma unroll
    for (int k = 0; k < NF; ++k) {
        unsigned long long m = __ballot(f == k);
        if (f == k) {
            int leader = __builtin_ctzll(m);
            int base = 0;
            if (lane == leader) base = atomicAdd(&cursors[k], __builtin_popcountll(m));
            base = __shfl(base, leader, 64);
            int rank = __builtin_popcountll(m & ((1ull << lane) - 1ull));
            perm[base + rank] = i;
        }
    }
}

__global__ __launch_bounds__(256) void k_main(
    const float* __restrict__ positions, const float* __restrict__ directions,
    const float* __restrict__ app,
    const float* __restrict__ Wd1, const float* __restrict__ bd1,
    const float* __restrict__ Wd2, const float* __restrict__ bd2,
    const float* __restrict__ Wc1, const float* __restrict__ bc1,
    const float* __restrict__ Wc2, const float* __restrict__ bc2,
    const int* __restrict__ ws, float* __restrict__ out) {
    const int f = blockIdx.x & 7;
    const int chunk = blockIdx.x >> 3;
    const int cnt = ws[f];
    const int start = ws[8 + f];
    const int* perm = ws + 32;

    const int tid = threadIdx.x;
    const int lane = tid & 63;
    const int w = tid >> 6;
    const int j0 = lane * 2;     // this lane's 2 hidden units
    const int o16 = lane & 15;   // layer-2 output index
    const int q16 = lane >> 4;   // layer-2 point index (within wave's 4)

    __shared__ float sWd2t[16 * 132];  // transposed Wd2[o][j], padded row 132
    __shared__ float sh[16][132];      // hidden h per (wave,point)
    __shared__ float scin[16][52];     // [dir(3) | geo(15) | app(32)] + pad
    __shared__ float spos[16][4];
    __shared__ int sidx[16];

    // Stage Wd2 transposed into LDS (coalesced global read).
    for (int e = tid; e < HID * 16; e += 256) {
        int j = e >> 4, o = e & 15;
        sWd2t[o * 132 + j] = Wd2[f * HID * 16 + e];
    }
    __syncthreads();

    // Per-lane register-resident weights (loaded once per block).
    const float2 bd1r = *(const float2*)&bd1[f * HID + j0];
    const float2 bc1r = *(const float2*)&bc1[f * HID + j0];
    const float bd2r = bd2[f * 16 + o16];
    const float2 wd1r0 = *(const float2*)&Wd1[f * 3 * HID + 0 * HID + j0];
    const float2 wd1r1 = *(const float2*)&Wd1[f * 3 * HID + 1 * HID + j0];
    const float2 wd1r2 = *(const float2*)&Wd1[f * 3 * HID + 2 * HID + j0];
    float wc2r[6];
#pragma unroll
    for (int t = 0; t < 6; ++t) wc2r[t] = Wc2[f * HID * 3 + j0 * 3 + t];
    const float bc2r0 = bc2[f * 3 + 0];
    const float bc2r1 = bc2[f * 3 + 1];
    const float bc2r2 = bc2[f * 3 + 2];
    float2 wc1r[NCIN];  // 100 VGPRs: the big win — no LDS/L2 traffic for Wc1
#pragma unroll
    for (int k = 0; k < NCIN; ++k)
        wc1r[k] = *(const float2*)&Wc1[f * NCIN * HID + k * HID + j0];

    for (int p0 = chunk * PPI; p0 < cnt; p0 += BPF * PPI) {
        wave_fence();  // prev-iter LDS reads done before we overwrite staging
        // ---- S1: gather 4 points' inputs into this wave's LDS staging ----
#pragma unroll
        for (int q = 0; q < 4; ++q) {
            int pl = p0 + w * 4 + q;
            if (pl < cnt) {
                int idx = perm[start + pl];
                int s = w * 4 + q;
                if (lane < 16) {
                    float2 a = *(const float2*)&app[idx * NAPP + 2 * lane];
                    *(float2*)&scin[s][18 + 2 * lane] = a;
                } else if (lane < 19) {
                    scin[s][lane - 16] = directions[idx * 3 + lane - 16];
                } else if (lane < 22) {
                    spos[s][lane - 19] = positions[idx * 3 + lane - 19];
                } else if (lane == 22) {
                    sidx[s] = idx;
                }
            }
        }
        wave_fence();

        // ---- S2: density layer 1 (3 -> 128), h kept per-lane, stored to LDS ----
#pragma unroll
        for (int q = 0; q < 4; ++q) {
            int s = w * 4 + q;
            float px = spos[s][0], py = spos[s][1], pz = spos[s][2];
            float h0 = fmaf(pz, wd1r2.x, fmaf(py, wd1r1.x, fmaf(px, wd1r0.x, bd1r.x)));
            float h1 = fmaf(pz, wd1r2.y, fmaf(py, wd1r1.y, fmaf(px, wd1r0.y, bd1r.y)));
            h0 = fmaxf(h0, 0.f);
            h1 = fmaxf(h1, 0.f);
            *(float2*)&sh[s][j0] = make_float2(h0, h1);
        }
        wave_fence();

        // ---- S3: density layer 2 (128 -> 16); lane handles (q16, o16) ----
        float dout = bd2r;
        {
            const float* hrow = &sh[w * 4 + q16][0];
            const float* wrow = &sWd2t[o16 * 132];
#pragma unroll
            for (int j4 = 0; j4 < 32; ++j4) {
                float4 hv = *(const float4*)&hrow[j4 * 4];
                float4 wv = *(const float4*)&wrow[j4 * 4];
                dout = fmaf(hv.x, wv.x, dout);
                dout = fmaf(hv.y, wv.y, dout);
                dout = fmaf(hv.z, wv.z, dout);
                dout = fmaf(hv.w, wv.w, dout);
            }
        }
        float dens = 0.f;
        if (o16 == 0) dens = __expf(dout);            // density = exp(dout[0])
        else scin[w * 4 + q16][2 + o16] = dout;       // geo -> cin[3..17]
        wave_fence();

        // ---- S4: color layer 1 (50 -> 128), weights in registers ----
        float hc[4][2];
#pragma unroll
        for (int q = 0; q < 4; ++q) { hc[q][0] = bc1r.x; hc[q][1] = bc1r.y; }
#pragma unroll
        for (int k4 = 0; k4 < 12; ++k4) {
            float4 c[4];
#pragma unroll
            for (int q = 0; q < 4; ++q) c[q] = *(const float4*)&scin[w * 4 + q][k4 * 4];
#pragma unroll
            for (int t = 0; t < 4; ++t) {
                float2 wv = wc1r[k4 * 4 + t];
#pragma unroll
                for (int q = 0; q < 4; ++q) {
                    float cv = (t == 0) ? c[q].x : (t == 1) ? c[q].y : (t == 2) ? c[q].z : c[q].w;
                    hc[q][0] = fmaf(cv, wv.x, hc[q][0]);
                    hc[q][1] = fmaf(cv, wv.y, hc[q][1]);
                }
            }
        }
#pragma unroll
        for (int q = 0; q < 4; ++q) {  // k = 48, 49 tail
            float2 ct = *(const float2*)&scin[w * 4 + q][48];
            hc[q][0] = fmaf(ct.x, wc1r[48].x, hc[q][0]);
            hc[q][1] = fmaf(ct.x, wc1r[48].y, hc[q][1]);
            hc[q][0] = fmaf(ct.y, wc1r[49].x, hc[q][0]);
            hc[q][1] = fmaf(ct.y, wc1r[49].y, hc[q][1]);
            hc[q][0] = fmaxf(hc[q][0], 0.f);
            hc[q][1] = fmaxf(hc[q][1], 0.f);
        }

        // ---- S5: color layer 2 (128 -> 3), butterfly reduce, write out ----
#pragma unroll
        for (int q = 0; q < 4; ++q) {
            float s0 = fmaf(hc[q][1], wc2r[3], hc[q][0] * wc2r[0]);
            float s1 = fmaf(hc[q][1], wc2r[4], hc[q][0] * wc2r[1]);
            float s2 = fmaf(hc[q][1], wc2r[5], hc[q][0] * wc2r[2]);
#pragma unroll
            for (int d = 1; d < 64; d <<= 1) {
                s0 += __shfl_xor(s0, d, 64);
                s1 += __shfl_xor(s1, d, 64);
                s2 += __shfl_xor(s2, d, 64);
            }
            if ((p0 + w * 4 + q) < cnt && lane == q * 16) {
                // this lane is (q16==q, o16==0): it owns dens for point q
                float4 o4;
                o4.x = dens;
                o4.y = 1.f / (1.f + __expf(-(s0 + bc2r0)));
                o4.z = 1.f / (1.f + __expf(-(s1 + bc2r1)));
                o4.w = 1.f / (1.f + __expf(-(s2 + bc2r2)));
                *(float4*)&out[sidx[w * 4 + q] * 4] = o4;
            }
        }
    }
}

extern "C" void kernel_launch(void* const* d_in, const int* in_sizes, int n_in,
                              void* d_out, int out_size, void* d_ws, size_t ws_size,
                              hipStream_t stream) {
    const float* positions = (const float*)d_in[0];
    const float* directions = (const float*)d_in[1];
    const float* app = (const float*)d_in[2];
    const float* centroids = (const float*)d_in[3];
    const float* Wd1 = (const float*)d_in[4];
    const float* bd1 = (const float*)d_in[5];
    const float* Wd2 = (const float*)d_in[6];
    const float* bd2 = (const float*)d_in[7];
    const float* Wc1 = (const float*)d_in[8];
    const float* bc1 = (const float*)d_in[9];
    const float* Wc2 = (const float*)d_in[10];
    const float* bc2 = (const float*)d_in[11];
    float* out = (float*)d_out;
    int* wsi = (int*)d_ws;
    const int n = in_sizes[0] / 3;

    hipMemsetAsync(d_ws, 0, 32 * sizeof(int), stream);
    int nb = (n + 255) / 256;
    k_count<<<nb, 256, 0, stream>>>(positions, centroids, n, wsi);
    k_scan<<<1, 64, 0, stream>>>(wsi);
    k_scatter<<<nb, 256, 0, stream>>>(positions, centroids, n, wsi);
    k_main<<<NF * BPF, 256, 0, stream>>>(positions, directions, app, Wd1, bd1, Wd2,
                                         bd2, Wc1, bc1, Wc2, bc2, wsi, out);
}

// Round 2
// 1980.096 us; speedup vs baseline: 1.9351x; 1.9351x over previous
//
#include <hip/hip_runtime.h>
#include <math.h>

#define NF 8
#define HID 128
#define NAPP 32
#define BPF 256  // chunks (blocks) per field in k_main

// ws int layout: [0..7] counts, [8..15] starts, [16..23] cursors, [32..] perm[N]

__device__ __forceinline__ int assign_field(float px, float py, float pz,
                                            const float* __restrict__ cen) {
    int best = 0;
    float bd = 3.4e38f;
#pragma unroll
    for (int k = 0; k < NF; ++k) {
        float dx = px - cen[k * 3 + 0];
        float dy = py - cen[k * 3 + 1];
        float dz = pz - cen[k * 3 + 2];
        float d = fmaf(dx, dx, fmaf(dy, dy, dz * dz));
        if (d < bd) { bd = d; best = k; }
    }
    return best;
}

__global__ void k_count(const float* __restrict__ pos, const float* __restrict__ cen,
                        int n, int* __restrict__ ws) {
    int i = blockIdx.x * blockDim.x + threadIdx.x;
    int lane = threadIdx.x & 63;
    int f = -1;
    if (i < n) f = assign_field(pos[3 * i], pos[3 * i + 1], pos[3 * i + 2], cen);
#pragma unroll
    for (int k = 0; k < NF; ++k) {
        unsigned long long m = __ballot(f == k);
        if (m != 0ull && lane == __builtin_ctzll(m))
            atomicAdd(&ws[k], __builtin_popcountll(m));
    }
}

__global__ void k_scan(int* __restrict__ ws) {
    if (threadIdx.x == 0 && blockIdx.x == 0) {
        int s = 0;
        for (int k = 0; k < NF; ++k) {
            int c = ws[k];
            ws[8 + k] = s;   // starts
            ws[16 + k] = s;  // cursors
            s += c;
        }
    }
}

__global__ void k_scatter(const float* __restrict__ pos, const float* __restrict__ cen,
                          int n, int* __restrict__ ws) {
    int i = blockIdx.x * blockDim.x + threadIdx.x;
    int lane = threadIdx.x & 63;
    int f = -1;
    if (i < n) f = assign_field(pos[3 * i], pos[3 * i + 1], pos[3 * i + 2], cen);
    int* cursors = ws + 16;
    int* perm = ws + 32;
#pragma unroll
    for (int k = 0; k < NF; ++k) {
        unsigned long long m = __ballot(f == k);
        if (f == k) {
            int leader = __builtin_ctzll(m);
            int base = 0;
            if (lane == leader) base = atomicAdd(&cursors[k], __builtin_popcountll(m));
            base = __shfl(base, leader, 64);
            int rank = __builtin_popcountll(m & ((1ull << lane) - 1ull));
            perm[base + rank] = i;
        }
    }
}

// One thread per point. Weights packed in LDS, read wave-uniform (broadcast).
// No barriers / fences / shuffles in the point loop.
__global__ __launch_bounds__(256) void k_main(
    const float* __restrict__ positions, const float* __restrict__ directions,
    const float* __restrict__ app,
    const float* __restrict__ Wd1, const float* __restrict__ bd1,
    const float* __restrict__ Wd2, const float* __restrict__ bd2,
    const float* __restrict__ Wc1, const float* __restrict__ bc1,
    const float* __restrict__ Wc2, const float* __restrict__ bc2,
    const int* __restrict__ ws, float* __restrict__ out) {
    const int f = blockIdx.x & 7;
    const int chunk = blockIdx.x >> 3;
    const int cnt = ws[f];
    if (chunk * 256 >= cnt) return;  // uniform early-exit (before staging)
    const int start = ws[8 + f];
    const int* perm = ws + 32;
    const int tid = threadIdx.x;

    __shared__ float sWd1p[HID * 4];       // {w0,w1,w2,bd1} per j          (2 KB)
    __shared__ float sWd2[HID * 16];       // native [j][16]                (8 KB)
    __shared__ float sWc1p[HID * 56];      // [j][56]: Wc1t(50),bc1,0,Wc2(3),0 (28 KB)
    __shared__ float sConst[32];           // [0..15]=bd2, [16..18]=bc2

    // ---- stage packed weights (once per block) ----
    if (tid < HID) {
        sWd1p[tid * 4 + 0] = Wd1[f * 3 * HID + 0 * HID + tid];
        sWd1p[tid * 4 + 1] = Wd1[f * 3 * HID + 1 * HID + tid];
        sWd1p[tid * 4 + 2] = Wd1[f * 3 * HID + 2 * HID + tid];
        sWd1p[tid * 4 + 3] = bd1[f * HID + tid];
    }
    for (int e = tid; e < HID * 16; e += 256) sWd2[e] = Wd2[f * HID * 16 + e];
    {
        int j = tid >> 1, half = tid & 1;
        if (half == 0) {
            for (int k = 0; k < 28; ++k)
                sWc1p[j * 56 + k] = Wc1[f * 50 * HID + k * HID + j];
        } else {
            for (int k = 28; k < 50; ++k)
                sWc1p[j * 56 + k] = Wc1[f * 50 * HID + k * HID + j];
            sWc1p[j * 56 + 50] = bc1[f * HID + j];
            sWc1p[j * 56 + 51] = 0.f;
            sWc1p[j * 56 + 52] = Wc2[f * HID * 3 + j * 3 + 0];
            sWc1p[j * 56 + 53] = Wc2[f * HID * 3 + j * 3 + 1];
            sWc1p[j * 56 + 54] = Wc2[f * HID * 3 + j * 3 + 2];
            sWc1p[j * 56 + 55] = 0.f;
        }
    }
    if (tid < 16) sConst[tid] = bd2[f * 16 + tid];
    else if (tid < 19) sConst[tid] = bc2[f * 3 + (tid - 16)];
    __syncthreads();

    // ---- point loop: one point per thread, fully independent ----
    for (int pl = chunk * 256 + tid; pl < cnt; pl += BPF * 256) {
        const int idx = perm[start + pl];

        // gather inputs (all independent loads)
        const float px = positions[idx * 3 + 0];
        const float py = positions[idx * 3 + 1];
        const float pz = positions[idx * 3 + 2];
        float cin[50];
        cin[0] = directions[idx * 3 + 0];
        cin[1] = directions[idx * 3 + 1];
        cin[2] = directions[idx * 3 + 2];
        const float4* ap = (const float4*)(app + idx * NAPP);
#pragma unroll
        for (int t = 0; t < 8; ++t) {
            float4 a = ap[t];
            cin[18 + 4 * t + 0] = a.x;
            cin[18 + 4 * t + 1] = a.y;
            cin[18 + 4 * t + 2] = a.z;
            cin[18 + 4 * t + 3] = a.w;
        }

        // density MLP: 3 -> 128 -> 16, hidden recomputed on the fly
        float dout[16];
#pragma unroll
        for (int o = 0; o < 16; ++o) dout[o] = sConst[o];
#pragma unroll 2
        for (int j = 0; j < HID; ++j) {
            float4 wd = *(const float4*)&sWd1p[j * 4];
            float h = fmaxf(fmaf(pz, wd.z, fmaf(py, wd.y, fmaf(px, wd.x, wd.w))), 0.f);
            const float* wr = &sWd2[j * 16];
            float4 w0 = *(const float4*)&wr[0];
            float4 w1 = *(const float4*)&wr[4];
            float4 w2 = *(const float4*)&wr[8];
            float4 w3 = *(const float4*)&wr[12];
            dout[0] = fmaf(h, w0.x, dout[0]);   dout[1] = fmaf(h, w0.y, dout[1]);
            dout[2] = fmaf(h, w0.z, dout[2]);   dout[3] = fmaf(h, w0.w, dout[3]);
            dout[4] = fmaf(h, w1.x, dout[4]);   dout[5] = fmaf(h, w1.y, dout[5]);
            dout[6] = fmaf(h, w1.z, dout[6]);   dout[7] = fmaf(h, w1.w, dout[7]);
            dout[8] = fmaf(h, w2.x, dout[8]);   dout[9] = fmaf(h, w2.y, dout[9]);
            dout[10] = fmaf(h, w2.z, dout[10]); dout[11] = fmaf(h, w2.w, dout[11]);
            dout[12] = fmaf(h, w3.x, dout[12]); dout[13] = fmaf(h, w3.y, dout[13]);
            dout[14] = fmaf(h, w3.z, dout[14]); dout[15] = fmaf(h, w3.w, dout[15]);
        }
        const float dens = __expf(dout[0]);
#pragma unroll
        for (int g = 0; g < 15; ++g) cin[3 + g] = dout[1 + g];

        // color MLP: 50 -> 128 -> 3, hidden consumed immediately
        float r0 = sConst[16], r1 = sConst[17], r2 = sConst[18];
#pragma unroll 2
        for (int j = 0; j < HID; ++j) {
            const float* row = &sWc1p[j * 56];
            float acc0 = 0.f, acc1 = 0.f;
#pragma unroll
            for (int kc = 0; kc < 12; kc += 2) {
                float4 u = *(const float4*)&row[kc * 4];
                float4 v = *(const float4*)&row[kc * 4 + 4];
                acc0 = fmaf(cin[kc * 4 + 0], u.x, acc0);
                acc0 = fmaf(cin[kc * 4 + 1], u.y, acc0);
                acc0 = fmaf(cin[kc * 4 + 2], u.z, acc0);
                acc0 = fmaf(cin[kc * 4 + 3], u.w, acc0);
                acc1 = fmaf(cin[kc * 4 + 4], v.x, acc1);
                acc1 = fmaf(cin[kc * 4 + 5], v.y, acc1);
                acc1 = fmaf(cin[kc * 4 + 6], v.z, acc1);
                acc1 = fmaf(cin[kc * 4 + 7], v.w, acc1);
            }
            {   // tail: cin[48], cin[49], bias (row[50]), row[51]=0
                float4 u = *(const float4*)&row[48];
                acc0 = fmaf(cin[48], u.x, acc0);
                acc1 = fmaf(cin[49], u.y, acc1);
                acc0 += u.z;  // bc1[j]
            }
            float hc = fmaxf(acc0 + acc1, 0.f);
            float4 cw = *(const float4*)&row[52];  // Wc2[j][0..2], 0
            r0 = fmaf(hc, cw.x, r0);
            r1 = fmaf(hc, cw.y, r1);
            r2 = fmaf(hc, cw.z, r2);
        }

        float4 o4;
        o4.x = dens;
        o4.y = 1.f / (1.f + __expf(-r0));
        o4.z = 1.f / (1.f + __expf(-r1));
        o4.w = 1.f / (1.f + __expf(-r2));
        *(float4*)&out[idx * 4] = o4;
    }
}

extern "C" void kernel_launch(void* const* d_in, const int* in_sizes, int n_in,
                              void* d_out, int out_size, void* d_ws, size_t ws_size,
                              hipStream_t stream) {
    const float* positions = (const float*)d_in[0];
    const float* directions = (const float*)d_in[1];
    const float* app = (const float*)d_in[2];
    const float* centroids = (const float*)d_in[3];
    const float* Wd1 = (const float*)d_in[4];
    const float* bd1 = (const float*)d_in[5];
    const float* Wd2 = (const float*)d_in[6];
    const float* bd2 = (const float*)d_in[7];
    const float* Wc1 = (const float*)d_in[8];
    const float* bc1 = (const float*)d_in[9];
    const float* Wc2 = (const float*)d_in[10];
    const float* bc2 = (const float*)d_in[11];
    float* out = (float*)d_out;
    int* wsi = (int*)d_ws;
    const int n = in_sizes[0] / 3;

    hipMemsetAsync(d_ws, 0, 32 * sizeof(int), stream);
    int nb = (n + 255) / 256;
    k_count<<<nb, 256, 0, stream>>>(positions, centroids, n, wsi);
    k_scan<<<1, 64, 0, stream>>>(wsi);
    k_scatter<<<nb, 256, 0, stream>>>(positions, centroids, n, wsi);
    k_main<<<NF * BPF, 256, 0, stream>>>(positions, directions, app, Wd1, bd1, Wd2,
                                         bd2, Wc1, bc1, Wc2, bc2, wsi, out);
}

// Round 3
// 501.582 us; speedup vs baseline: 7.6394x; 3.9477x over previous
//
#include <hip/hip_runtime.h>
#include <math.h>

#define NF 8
#define HID 128
#define NAPP 32
#define PB 128   // blocks per field in k_main (2 points/thread)

// ws int layout:
//   [0..7]   field counts
//   [8..15]  field starts
//   [32 .. 32+NB*8)        per-block-per-field counts -> (after scan) write offsets
//   [32+NB*8 .. +N)        perm

__device__ __forceinline__ int assign_field(float px, float py, float pz,
                                            const float* __restrict__ cen) {
    int best = 0;
    float bd = 3.4e38f;
#pragma unroll
    for (int k = 0; k < NF; ++k) {
        float dx = px - cen[k * 3 + 0];
        float dy = py - cen[k * 3 + 1];
        float dz = pz - cen[k * 3 + 2];
        float d = fmaf(dx, dx, fmaf(dy, dy, dz * dz));
        if (d < bd) { bd = d; best = k; }
    }
    return best;
}

// Per-block counts; no global atomics.
__global__ void k_count(const float* __restrict__ pos, const float* __restrict__ cen,
                        int n, int* __restrict__ blockcnt) {
    __shared__ int lc[NF];
    int tid = threadIdx.x;
    if (tid < NF) lc[tid] = 0;
    __syncthreads();
    int i = blockIdx.x * blockDim.x + tid;
    int lane = tid & 63;
    int f = -1;
    if (i < n) f = assign_field(pos[3 * i], pos[3 * i + 1], pos[3 * i + 2], cen);
#pragma unroll
    for (int k = 0; k < NF; ++k) {
        unsigned long long m = __ballot(f == k);
        if (m != 0ull && lane == __builtin_ctzll(m))
            atomicAdd(&lc[k], __builtin_popcountll(m));  // LDS atomic only
    }
    __syncthreads();
    if (tid < NF) blockcnt[blockIdx.x * NF + tid] = lc[tid];
}

// One block, 512 threads = 8 waves; wave w owns field w.
// Turns blockcnt into per-block exclusive write offsets; writes counts/starts.
__global__ void k_scan(int* __restrict__ ws, int nb) {
    int f = threadIdx.x >> 6;
    int lane = threadIdx.x & 63;
    int* c = ws + 32;
    __shared__ int totals[NF];
    __shared__ int starts[NF];

    int tot = 0;
    for (int b = lane; b < nb; b += 64) tot += c[b * NF + f];
#pragma unroll
    for (int d = 1; d < 64; d <<= 1) tot += __shfl_xor(tot, d, 64);
    if (lane == 0) totals[f] = tot;
    __syncthreads();
    if (threadIdx.x == 0) {
        int s = 0;
        for (int k = 0; k < NF; ++k) {
            starts[k] = s;
            ws[k] = totals[k];
            ws[8 + k] = s;
            s += totals[k];
        }
    }
    __syncthreads();
    int run = starts[f];
    for (int b0 = 0; b0 < nb; b0 += 64) {
        int b = b0 + lane;
        int v = (b < nb) ? c[b * NF + f] : 0;
        int inc = v;
#pragma unroll
        for (int d = 1; d < 64; d <<= 1) {
            int t = __shfl_up(inc, d, 64);
            if (lane >= d) inc += t;
        }
        if (b < nb) c[b * NF + f] = run + (inc - v);
        run += __shfl(inc, 63, 64);
    }
}

// Scatter using LDS cursors seeded from scanned offsets; no global atomics.
__global__ void k_scatter(const float* __restrict__ pos, const float* __restrict__ cen,
                          int n, int nb, int* __restrict__ ws) {
    __shared__ int cur[NF];
    int tid = threadIdx.x;
    int* gofs = ws + 32;
    int* perm = ws + 32 + nb * NF;
    if (tid < NF) cur[tid] = gofs[blockIdx.x * NF + tid];
    __syncthreads();
    int i = blockIdx.x * blockDim.x + tid;
    int lane = tid & 63;
    int f = -1;
    if (i < n) f = assign_field(pos[3 * i], pos[3 * i + 1], pos[3 * i + 2], cen);
#pragma unroll
    for (int k = 0; k < NF; ++k) {
        unsigned long long m = __ballot(f == k);
        if (f == k) {
            int leader = __builtin_ctzll(m);
            int base = 0;
            if (lane == leader) base = atomicAdd(&cur[k], __builtin_popcountll(m));
            base = __shfl(base, leader, 64);
            int rank = __builtin_popcountll(m & ((1ull << lane) - 1ull));
            perm[base + rank] = i;
        }
    }
}

// One thread per TWO points; weights in LDS, wave-uniform broadcast reads.
__global__ __launch_bounds__(256) void k_main(
    const float* __restrict__ positions, const float* __restrict__ directions,
    const float* __restrict__ app,
    const float* __restrict__ Wd1, const float* __restrict__ bd1,
    const float* __restrict__ Wd2, const float* __restrict__ bd2,
    const float* __restrict__ Wc1, const float* __restrict__ bc1,
    const float* __restrict__ Wc2, const float* __restrict__ bc2,
    const int* __restrict__ ws, int nb, float* __restrict__ out) {
    const int f = blockIdx.x & 7;
    const int chunk = blockIdx.x >> 3;
    const int cnt = ws[f];
    if (chunk * 512 >= cnt) return;
    const int start = ws[8 + f];
    const int* perm = ws + 32 + nb * NF;
    const int tid = threadIdx.x;

    __shared__ float sWd1p[HID * 4];   // {w0,w1,w2,bd1} per j
    __shared__ float sWd2[HID * 16];   // native [j][16]
    __shared__ float sWc1p[HID * 56];  // [j][56]: Wc1t(50),bc1,0,Wc2(3),0
    __shared__ float sConst[32];       // [0..15]=bd2, [16..18]=bc2

    if (tid < HID) {
        sWd1p[tid * 4 + 0] = Wd1[f * 3 * HID + 0 * HID + tid];
        sWd1p[tid * 4 + 1] = Wd1[f * 3 * HID + 1 * HID + tid];
        sWd1p[tid * 4 + 2] = Wd1[f * 3 * HID + 2 * HID + tid];
        sWd1p[tid * 4 + 3] = bd1[f * HID + tid];
    }
    for (int e = tid; e < HID * 16; e += 256) sWd2[e] = Wd2[f * HID * 16 + e];
    {
        int j = tid >> 1, half = tid & 1;
        if (half == 0) {
            for (int k = 0; k < 28; ++k)
                sWc1p[j * 56 + k] = Wc1[f * 50 * HID + k * HID + j];
        } else {
            for (int k = 28; k < 50; ++k)
                sWc1p[j * 56 + k] = Wc1[f * 50 * HID + k * HID + j];
            sWc1p[j * 56 + 50] = bc1[f * HID + j];
            sWc1p[j * 56 + 51] = 0.f;
            sWc1p[j * 56 + 52] = Wc2[f * HID * 3 + j * 3 + 0];
            sWc1p[j * 56 + 53] = Wc2[f * HID * 3 + j * 3 + 1];
            sWc1p[j * 56 + 54] = Wc2[f * HID * 3 + j * 3 + 2];
            sWc1p[j * 56 + 55] = 0.f;
        }
    }
    if (tid < 16) sConst[tid] = bd2[f * 16 + tid];
    else if (tid < 19) sConst[tid] = bc2[f * 3 + (tid - 16)];
    __syncthreads();

    for (int pl = chunk * 512 + tid; pl < cnt; pl += PB * 512) {
        const int pl2 = pl + 256;
        const bool has2 = (pl2 < cnt);
        const int idx0 = perm[start + pl];
        const int idx1 = has2 ? perm[start + pl2] : idx0;

        const float px0 = positions[idx0 * 3 + 0];
        const float py0 = positions[idx0 * 3 + 1];
        const float pz0 = positions[idx0 * 3 + 2];
        const float px1 = positions[idx1 * 3 + 0];
        const float py1 = positions[idx1 * 3 + 1];
        const float pz1 = positions[idx1 * 3 + 2];
        float cin0[50], cin1[50];
        cin0[0] = directions[idx0 * 3 + 0];
        cin0[1] = directions[idx0 * 3 + 1];
        cin0[2] = directions[idx0 * 3 + 2];
        cin1[0] = directions[idx1 * 3 + 0];
        cin1[1] = directions[idx1 * 3 + 1];
        cin1[2] = directions[idx1 * 3 + 2];
        const float4* ap0 = (const float4*)(app + idx0 * NAPP);
        const float4* ap1 = (const float4*)(app + idx1 * NAPP);
#pragma unroll
        for (int t = 0; t < 8; ++t) {
            float4 a = ap0[t];
            cin0[18 + 4 * t + 0] = a.x; cin0[18 + 4 * t + 1] = a.y;
            cin0[18 + 4 * t + 2] = a.z; cin0[18 + 4 * t + 3] = a.w;
            float4 b = ap1[t];
            cin1[18 + 4 * t + 0] = b.x; cin1[18 + 4 * t + 1] = b.y;
            cin1[18 + 4 * t + 2] = b.z; cin1[18 + 4 * t + 3] = b.w;
        }

        // density MLP: 3 -> 128 -> 16 for both points, shared weight loads
        float dout0[16], dout1[16];
#pragma unroll
        for (int o = 0; o < 16; ++o) { dout0[o] = sConst[o]; dout1[o] = sConst[o]; }
#pragma unroll 2
        for (int j = 0; j < HID; ++j) {
            float4 wd = *(const float4*)&sWd1p[j * 4];
            float h0 = fmaxf(fmaf(pz0, wd.z, fmaf(py0, wd.y, fmaf(px0, wd.x, wd.w))), 0.f);
            float h1 = fmaxf(fmaf(pz1, wd.z, fmaf(py1, wd.y, fmaf(px1, wd.x, wd.w))), 0.f);
            const float* wr = &sWd2[j * 16];
            float4 w0 = *(const float4*)&wr[0];
            float4 w1 = *(const float4*)&wr[4];
            float4 w2 = *(const float4*)&wr[8];
            float4 w3 = *(const float4*)&wr[12];
            dout0[0] = fmaf(h0, w0.x, dout0[0]);   dout1[0] = fmaf(h1, w0.x, dout1[0]);
            dout0[1] = fmaf(h0, w0.y, dout0[1]);   dout1[1] = fmaf(h1, w0.y, dout1[1]);
            dout0[2] = fmaf(h0, w0.z, dout0[2]);   dout1[2] = fmaf(h1, w0.z, dout1[2]);
            dout0[3] = fmaf(h0, w0.w, dout0[3]);   dout1[3] = fmaf(h1, w0.w, dout1[3]);
            dout0[4] = fmaf(h0, w1.x, dout0[4]);   dout1[4] = fmaf(h1, w1.x, dout1[4]);
            dout0[5] = fmaf(h0, w1.y, dout0[5]);   dout1[5] = fmaf(h1, w1.y, dout1[5]);
            dout0[6] = fmaf(h0, w1.z, dout0[6]);   dout1[6] = fmaf(h1, w1.z, dout1[6]);
            dout0[7] = fmaf(h0, w1.w, dout0[7]);   dout1[7] = fmaf(h1, w1.w, dout1[7]);
            dout0[8] = fmaf(h0, w2.x, dout0[8]);   dout1[8] = fmaf(h1, w2.x, dout1[8]);
            dout0[9] = fmaf(h0, w2.y, dout0[9]);   dout1[9] = fmaf(h1, w2.y, dout1[9]);
            dout0[10] = fmaf(h0, w2.z, dout0[10]); dout1[10] = fmaf(h1, w2.z, dout1[10]);
            dout0[11] = fmaf(h0, w2.w, dout0[11]); dout1[11] = fmaf(h1, w2.w, dout1[11]);
            dout0[12] = fmaf(h0, w3.x, dout0[12]); dout1[12] = fmaf(h1, w3.x, dout1[12]);
            dout0[13] = fmaf(h0, w3.y, dout0[13]); dout1[13] = fmaf(h1, w3.y, dout1[13]);
            dout0[14] = fmaf(h0, w3.z, dout0[14]); dout1[14] = fmaf(h1, w3.z, dout1[14]);
            dout0[15] = fmaf(h0, w3.w, dout0[15]); dout1[15] = fmaf(h1, w3.w, dout1[15]);
        }
        const float dens0 = __expf(dout0[0]);
        const float dens1 = __expf(dout1[0]);
#pragma unroll
        for (int g = 0; g < 15; ++g) { cin0[3 + g] = dout0[1 + g]; cin1[3 + g] = dout1[1 + g]; }

        // color MLP: 50 -> 128 -> 3 for both points, shared weight loads
        float r00 = sConst[16], r01 = sConst[17], r02 = sConst[18];
        float r10 = sConst[16], r11 = sConst[17], r12 = sConst[18];
#pragma unroll 2
        for (int j = 0; j < HID; ++j) {
            const float* row = &sWc1p[j * 56];
            float a0 = 0.f, a1 = 0.f, b0 = 0.f, b1 = 0.f;
#pragma unroll
            for (int kc = 0; kc < 12; kc += 2) {
                float4 u = *(const float4*)&row[kc * 4];
                float4 v = *(const float4*)&row[kc * 4 + 4];
                a0 = fmaf(cin0[kc * 4 + 0], u.x, a0);  b0 = fmaf(cin1[kc * 4 + 0], u.x, b0);
                a0 = fmaf(cin0[kc * 4 + 1], u.y, a0);  b0 = fmaf(cin1[kc * 4 + 1], u.y, b0);
                a0 = fmaf(cin0[kc * 4 + 2], u.z, a0);  b0 = fmaf(cin1[kc * 4 + 2], u.z, b0);
                a0 = fmaf(cin0[kc * 4 + 3], u.w, a0);  b0 = fmaf(cin1[kc * 4 + 3], u.w, b0);
                a1 = fmaf(cin0[kc * 4 + 4], v.x, a1);  b1 = fmaf(cin1[kc * 4 + 4], v.x, b1);
                a1 = fmaf(cin0[kc * 4 + 5], v.y, a1);  b1 = fmaf(cin1[kc * 4 + 5], v.y, b1);
                a1 = fmaf(cin0[kc * 4 + 6], v.z, a1);  b1 = fmaf(cin1[kc * 4 + 6], v.z, b1);
                a1 = fmaf(cin0[kc * 4 + 7], v.w, a1);  b1 = fmaf(cin1[kc * 4 + 7], v.w, b1);
            }
            {
                float4 u = *(const float4*)&row[48];  // cin48 w, cin49 w, bc1, 0
                a0 = fmaf(cin0[48], u.x, a0);  b0 = fmaf(cin1[48], u.x, b0);
                a1 = fmaf(cin0[49], u.y, a1);  b1 = fmaf(cin1[49], u.y, b1);
                a0 += u.z;  b0 += u.z;
            }
            float hc0 = fmaxf(a0 + a1, 0.f);
            float hc1 = fmaxf(b0 + b1, 0.f);
            float4 cw = *(const float4*)&row[52];
            r00 = fmaf(hc0, cw.x, r00);  r10 = fmaf(hc1, cw.x, r10);
            r01 = fmaf(hc0, cw.y, r01);  r11 = fmaf(hc1, cw.y, r11);
            r02 = fmaf(hc0, cw.z, r02);  r12 = fmaf(hc1, cw.z, r12);
        }

        float4 o4;
        o4.x = dens0;
        o4.y = 1.f / (1.f + __expf(-r00));
        o4.z = 1.f / (1.f + __expf(-r01));
        o4.w = 1.f / (1.f + __expf(-r02));
        *(float4*)&out[idx0 * 4] = o4;
        if (has2) {
            float4 o5;
            o5.x = dens1;
            o5.y = 1.f / (1.f + __expf(-r10));
            o5.z = 1.f / (1.f + __expf(-r11));
            o5.w = 1.f / (1.f + __expf(-r12));
            *(float4*)&out[idx1 * 4] = o5;
        }
    }
}

extern "C" void kernel_launch(void* const* d_in, const int* in_sizes, int n_in,
                              void* d_out, int out_size, void* d_ws, size_t ws_size,
                              hipStream_t stream) {
    const float* positions = (const float*)d_in[0];
    const float* directions = (const float*)d_in[1];
    const float* app = (const float*)d_in[2];
    const float* centroids = (const float*)d_in[3];
    const float* Wd1 = (const float*)d_in[4];
    const float* bd1 = (const float*)d_in[5];
    const float* Wd2 = (const float*)d_in[6];
    const float* bd2 = (const float*)d_in[7];
    const float* Wc1 = (const float*)d_in[8];
    const float* bc1 = (const float*)d_in[9];
    const float* Wc2 = (const float*)d_in[10];
    const float* bc2 = (const float*)d_in[11];
    float* out = (float*)d_out;
    int* wsi = (int*)d_ws;
    const int n = in_sizes[0] / 3;
    const int nb = (n + 255) / 256;

    k_count<<<nb, 256, 0, stream>>>(positions, centroids, n, wsi + 32);
    k_scan<<<1, 512, 0, stream>>>(wsi, nb);
    k_scatter<<<nb, 256, 0, stream>>>(positions, centroids, n, nb, wsi);
    k_main<<<NF * PB, 256, 0, stream>>>(positions, directions, app, Wd1, bd1, Wd2,
                                        bd2, Wc1, bc1, Wc2, bc2, wsi, nb, out);
}

// Round 4
// 294.803 us; speedup vs baseline: 12.9978x; 1.7014x over previous
//
#include <hip/hip_runtime.h>
#include <math.h>

#define NF 8
#define HID 128
#define NAPP 32
#define TILE 512   // points per k_main block (2 per thread)

// ws int layout:
//   [0..7]   field counts
//   [8..15]  field starts
//   [16..23] field tile-prefix; [24] total tiles
//   [32 .. 32+NB*8)   per-block-per-field counts -> (after scan) write offsets
//   [32+NB*8 .. +N)   perm

__device__ __forceinline__ int assign_field(float px, float py, float pz,
                                            const float* __restrict__ cen) {
    int best = 0;
    float bd = 3.4e38f;
#pragma unroll
    for (int k = 0; k < NF; ++k) {
        float dx = px - cen[k * 3 + 0];
        float dy = py - cen[k * 3 + 1];
        float dz = pz - cen[k * 3 + 2];
        float d = fmaf(dx, dx, fmaf(dy, dy, dz * dz));
        if (d < bd) { bd = d; best = k; }
    }
    return best;
}

// Per-block counts; no global atomics.
__global__ void k_count(const float* __restrict__ pos, const float* __restrict__ cen,
                        int n, int* __restrict__ blockcnt) {
    __shared__ int lc[NF];
    int tid = threadIdx.x;
    if (tid < NF) lc[tid] = 0;
    __syncthreads();
    int i = blockIdx.x * blockDim.x + tid;
    int lane = tid & 63;
    int f = -1;
    if (i < n) f = assign_field(pos[3 * i], pos[3 * i + 1], pos[3 * i + 2], cen);
#pragma unroll
    for (int k = 0; k < NF; ++k) {
        unsigned long long m = __ballot(f == k);
        if (m != 0ull && lane == __builtin_ctzll(m))
            atomicAdd(&lc[k], __builtin_popcountll(m));  // LDS atomic only
    }
    __syncthreads();
    if (tid < NF) blockcnt[blockIdx.x * NF + tid] = lc[tid];
}

// One block, 512 threads = 8 waves; wave w owns field w.
__global__ void k_scan(int* __restrict__ ws, int nb) {
    int f = threadIdx.x >> 6;
    int lane = threadIdx.x & 63;
    int* c = ws + 32;
    __shared__ int totals[NF];
    __shared__ int starts[NF];

    int tot = 0;
    for (int b = lane; b < nb; b += 64) tot += c[b * NF + f];
#pragma unroll
    for (int d = 1; d < 64; d <<= 1) tot += __shfl_xor(tot, d, 64);
    if (lane == 0) totals[f] = tot;
    __syncthreads();
    if (threadIdx.x == 0) {
        int s = 0, tp = 0;
        for (int k = 0; k < NF; ++k) {
            starts[k] = s;
            ws[k] = totals[k];
            ws[8 + k] = s;
            ws[16 + k] = tp;                       // tile prefix
            s += totals[k];
            tp += (totals[k] + TILE - 1) / TILE;
        }
        ws[24] = tp;                               // total tiles
    }
    __syncthreads();
    int run = starts[f];
    for (int b0 = 0; b0 < nb; b0 += 64) {
        int b = b0 + lane;
        int v = (b < nb) ? c[b * NF + f] : 0;
        int inc = v;
#pragma unroll
        for (int d = 1; d < 64; d <<= 1) {
            int t = __shfl_up(inc, d, 64);
            if (lane >= d) inc += t;
        }
        if (b < nb) c[b * NF + f] = run + (inc - v);
        run += __shfl(inc, 63, 64);
    }
}

// Scatter using LDS cursors seeded from scanned offsets; no global atomics.
__global__ void k_scatter(const float* __restrict__ pos, const float* __restrict__ cen,
                          int n, int nb, int* __restrict__ ws) {
    __shared__ int cur[NF];
    int tid = threadIdx.x;
    int* gofs = ws + 32;
    int* perm = ws + 32 + nb * NF;
    if (tid < NF) cur[tid] = gofs[blockIdx.x * NF + tid];
    __syncthreads();
    int i = blockIdx.x * blockDim.x + tid;
    int lane = tid & 63;
    int f = -1;
    if (i < n) f = assign_field(pos[3 * i], pos[3 * i + 1], pos[3 * i + 2], cen);
#pragma unroll
    for (int k = 0; k < NF; ++k) {
        unsigned long long m = __ballot(f == k);
        if (f == k) {
            int leader = __builtin_ctzll(m);
            int base = 0;
            if (lane == leader) base = atomicAdd(&cur[k], __builtin_popcountll(m));
            base = __shfl(base, leader, 64);
            int rank = __builtin_popcountll(m & ((1ull << lane) - 1ull));
            perm[base + rank] = i;
        }
    }
}

// One block = one 512-point tile of one field; 2 points per thread.
// __launch_bounds__(256,2): VGPR cap 256 so the cin arrays stay in registers
// (R3's cap of 80 spilled ~100 floats/thread to scratch in the inner loop).
__global__ __launch_bounds__(256, 2) void k_main(
    const float* __restrict__ positions, const float* __restrict__ directions,
    const float* __restrict__ app,
    const float* __restrict__ Wd1, const float* __restrict__ bd1,
    const float* __restrict__ Wd2, const float* __restrict__ bd2,
    const float* __restrict__ Wc1, const float* __restrict__ bc1,
    const float* __restrict__ Wc2, const float* __restrict__ bc2,
    const int* __restrict__ ws, int nb, float* __restrict__ out) {
    const int b = blockIdx.x;
    if (b >= ws[24]) return;
    int f = 0;
#pragma unroll
    for (int k = 1; k < NF; ++k) if (b >= ws[16 + k]) f = k;
    const int tile = b - ws[16 + f];
    const int cnt = ws[f];
    const int start = ws[8 + f];
    const int* perm = ws + 32 + nb * NF;
    const int tid = threadIdx.x;

    __shared__ float sWd1p[HID * 4];   // {w0,w1,w2,bd1} per j
    __shared__ float sWd2[HID * 16];   // native [j][16]
    __shared__ float sWc1p[HID * 56];  // [j][56]: Wc1t(50),bc1,0,Wc2(3),0
    __shared__ float sConst[32];       // [0..15]=bd2, [16..18]=bc2

    if (tid < HID) {
        sWd1p[tid * 4 + 0] = Wd1[f * 3 * HID + 0 * HID + tid];
        sWd1p[tid * 4 + 1] = Wd1[f * 3 * HID + 1 * HID + tid];
        sWd1p[tid * 4 + 2] = Wd1[f * 3 * HID + 2 * HID + tid];
        sWd1p[tid * 4 + 3] = bd1[f * HID + tid];
    }
    for (int e = tid; e < HID * 16; e += 256) sWd2[e] = Wd2[f * HID * 16 + e];
    {
        int j = tid >> 1, half = tid & 1;
        if (half == 0) {
            for (int k = 0; k < 28; ++k)
                sWc1p[j * 56 + k] = Wc1[f * 50 * HID + k * HID + j];
        } else {
            for (int k = 28; k < 50; ++k)
                sWc1p[j * 56 + k] = Wc1[f * 50 * HID + k * HID + j];
            sWc1p[j * 56 + 50] = bc1[f * HID + j];
            sWc1p[j * 56 + 51] = 0.f;
            sWc1p[j * 56 + 52] = Wc2[f * HID * 3 + j * 3 + 0];
            sWc1p[j * 56 + 53] = Wc2[f * HID * 3 + j * 3 + 1];
            sWc1p[j * 56 + 54] = Wc2[f * HID * 3 + j * 3 + 2];
            sWc1p[j * 56 + 55] = 0.f;
        }
    }
    if (tid < 16) sConst[tid] = bd2[f * 16 + tid];
    else if (tid < 19) sConst[tid] = bc2[f * 3 + (tid - 16)];
    __syncthreads();

    const int pl = tile * TILE + tid;
    const int pl2 = pl + 256;
    const bool v0 = (pl < cnt);
    const bool v1 = (pl2 < cnt);
    const int idx0 = perm[start + (v0 ? pl : cnt - 1)];
    const int idx1 = perm[start + (v1 ? pl2 : cnt - 1)];

    const float px0 = positions[idx0 * 3 + 0];
    const float py0 = positions[idx0 * 3 + 1];
    const float pz0 = positions[idx0 * 3 + 2];
    const float px1 = positions[idx1 * 3 + 0];
    const float py1 = positions[idx1 * 3 + 1];
    const float pz1 = positions[idx1 * 3 + 2];
    float cin0[50], cin1[50];
    cin0[0] = directions[idx0 * 3 + 0];
    cin0[1] = directions[idx0 * 3 + 1];
    cin0[2] = directions[idx0 * 3 + 2];
    cin1[0] = directions[idx1 * 3 + 0];
    cin1[1] = directions[idx1 * 3 + 1];
    cin1[2] = directions[idx1 * 3 + 2];
    const float4* ap0 = (const float4*)(app + idx0 * NAPP);
    const float4* ap1 = (const float4*)(app + idx1 * NAPP);
#pragma unroll
    for (int t = 0; t < 8; ++t) {
        float4 a = ap0[t];
        cin0[18 + 4 * t + 0] = a.x; cin0[18 + 4 * t + 1] = a.y;
        cin0[18 + 4 * t + 2] = a.z; cin0[18 + 4 * t + 3] = a.w;
        float4 c = ap1[t];
        cin1[18 + 4 * t + 0] = c.x; cin1[18 + 4 * t + 1] = c.y;
        cin1[18 + 4 * t + 2] = c.z; cin1[18 + 4 * t + 3] = c.w;
    }

    // density MLP: 3 -> 128 -> 16 for both points, shared weight loads
    float dout0[16], dout1[16];
#pragma unroll
    for (int o = 0; o < 16; ++o) { dout0[o] = sConst[o]; dout1[o] = sConst[o]; }
#pragma unroll 2
    for (int j = 0; j < HID; ++j) {
        float4 wd = *(const float4*)&sWd1p[j * 4];
        float h0 = fmaxf(fmaf(pz0, wd.z, fmaf(py0, wd.y, fmaf(px0, wd.x, wd.w))), 0.f);
        float h1 = fmaxf(fmaf(pz1, wd.z, fmaf(py1, wd.y, fmaf(px1, wd.x, wd.w))), 0.f);
        const float* wr = &sWd2[j * 16];
        float4 w0 = *(const float4*)&wr[0];
        float4 w1 = *(const float4*)&wr[4];
        float4 w2 = *(const float4*)&wr[8];
        float4 w3 = *(const float4*)&wr[12];
        dout0[0] = fmaf(h0, w0.x, dout0[0]);   dout1[0] = fmaf(h1, w0.x, dout1[0]);
        dout0[1] = fmaf(h0, w0.y, dout0[1]);   dout1[1] = fmaf(h1, w0.y, dout1[1]);
        dout0[2] = fmaf(h0, w0.z, dout0[2]);   dout1[2] = fmaf(h1, w0.z, dout1[2]);
        dout0[3] = fmaf(h0, w0.w, dout0[3]);   dout1[3] = fmaf(h1, w0.w, dout1[3]);
        dout0[4] = fmaf(h0, w1.x, dout0[4]);   dout1[4] = fmaf(h1, w1.x, dout1[4]);
        dout0[5] = fmaf(h0, w1.y, dout0[5]);   dout1[5] = fmaf(h1, w1.y, dout1[5]);
        dout0[6] = fmaf(h0, w1.z, dout0[6]);   dout1[6] = fmaf(h1, w1.z, dout1[6]);
        dout0[7] = fmaf(h0, w1.w, dout0[7]);   dout1[7] = fmaf(h1, w1.w, dout1[7]);
        dout0[8] = fmaf(h0, w2.x, dout0[8]);   dout1[8] = fmaf(h1, w2.x, dout1[8]);
        dout0[9] = fmaf(h0, w2.y, dout0[9]);   dout1[9] = fmaf(h1, w2.y, dout1[9]);
        dout0[10] = fmaf(h0, w2.z, dout0[10]); dout1[10] = fmaf(h1, w2.z, dout1[10]);
        dout0[11] = fmaf(h0, w2.w, dout0[11]); dout1[11] = fmaf(h1, w2.w, dout1[11]);
        dout0[12] = fmaf(h0, w3.x, dout0[12]); dout1[12] = fmaf(h1, w3.x, dout1[12]);
        dout0[13] = fmaf(h0, w3.y, dout0[13]); dout1[13] = fmaf(h1, w3.y, dout1[13]);
        dout0[14] = fmaf(h0, w3.z, dout0[14]); dout1[14] = fmaf(h1, w3.z, dout1[14]);
        dout0[15] = fmaf(h0, w3.w, dout0[15]); dout1[15] = fmaf(h1, w3.w, dout1[15]);
    }
    const float dens0 = __expf(dout0[0]);
    const float dens1 = __expf(dout1[0]);
#pragma unroll
    for (int g = 0; g < 15; ++g) { cin0[3 + g] = dout0[1 + g]; cin1[3 + g] = dout1[1 + g]; }

    // color MLP: 50 -> 128 -> 3 for both points, shared weight loads
    float r00 = sConst[16], r01 = sConst[17], r02 = sConst[18];
    float r10 = sConst[16], r11 = sConst[17], r12 = sConst[18];
#pragma unroll 2
    for (int j = 0; j < HID; ++j) {
        const float* row = &sWc1p[j * 56];
        float a0 = 0.f, a1 = 0.f, b0 = 0.f, b1 = 0.f;
#pragma unroll
        for (int kc = 0; kc < 12; kc += 2) {
            float4 u = *(const float4*)&row[kc * 4];
            float4 v = *(const float4*)&row[kc * 4 + 4];
            a0 = fmaf(cin0[kc * 4 + 0], u.x, a0);  b0 = fmaf(cin1[kc * 4 + 0], u.x, b0);
            a0 = fmaf(cin0[kc * 4 + 1], u.y, a0);  b0 = fmaf(cin1[kc * 4 + 1], u.y, b0);
            a0 = fmaf(cin0[kc * 4 + 2], u.z, a0);  b0 = fmaf(cin1[kc * 4 + 2], u.z, b0);
            a0 = fmaf(cin0[kc * 4 + 3], u.w, a0);  b0 = fmaf(cin1[kc * 4 + 3], u.w, b0);
            a1 = fmaf(cin0[kc * 4 + 4], v.x, a1);  b1 = fmaf(cin1[kc * 4 + 4], v.x, b1);
            a1 = fmaf(cin0[kc * 4 + 5], v.y, a1);  b1 = fmaf(cin1[kc * 4 + 5], v.y, b1);
            a1 = fmaf(cin0[kc * 4 + 6], v.z, a1);  b1 = fmaf(cin1[kc * 4 + 6], v.z, b1);
            a1 = fmaf(cin0[kc * 4 + 7], v.w, a1);  b1 = fmaf(cin1[kc * 4 + 7], v.w, b1);
        }
        {
            float4 u = *(const float4*)&row[48];  // cin48 w, cin49 w, bc1, 0
            a0 = fmaf(cin0[48], u.x, a0);  b0 = fmaf(cin1[48], u.x, b0);
            a1 = fmaf(cin0[49], u.y, a1);  b1 = fmaf(cin1[49], u.y, b1);
            a0 += u.z;  b0 += u.z;
        }
        float hc0 = fmaxf(a0 + a1, 0.f);
        float hc1 = fmaxf(b0 + b1, 0.f);
        float4 cw = *(const float4*)&row[52];
        r00 = fmaf(hc0, cw.x, r00);  r10 = fmaf(hc1, cw.x, r10);
        r01 = fmaf(hc0, cw.y, r01);  r11 = fmaf(hc1, cw.y, r11);
        r02 = fmaf(hc0, cw.z, r02);  r12 = fmaf(hc1, cw.z, r12);
    }

    if (v0) {
        float4 o4;
        o4.x = dens0;
        o4.y = 1.f / (1.f + __expf(-r00));
        o4.z = 1.f / (1.f + __expf(-r01));
        o4.w = 1.f / (1.f + __expf(-r02));
        *(float4*)&out[idx0 * 4] = o4;
    }
    if (v1) {
        float4 o5;
        o5.x = dens1;
        o5.y = 1.f / (1.f + __expf(-r10));
        o5.z = 1.f / (1.f + __expf(-r11));
        o5.w = 1.f / (1.f + __expf(-r12));
        *(float4*)&out[idx1 * 4] = o5;
    }
}

extern "C" void kernel_launch(void* const* d_in, const int* in_sizes, int n_in,
                              void* d_out, int out_size, void* d_ws, size_t ws_size,
                              hipStream_t stream) {
    const float* positions = (const float*)d_in[0];
    const float* directions = (const float*)d_in[1];
    const float* app = (const float*)d_in[2];
    const float* centroids = (const float*)d_in[3];
    const float* Wd1 = (const float*)d_in[4];
    const float* bd1 = (const float*)d_in[5];
    const float* Wd2 = (const float*)d_in[6];
    const float* bd2 = (const float*)d_in[7];
    const float* Wc1 = (const float*)d_in[8];
    const float* bc1 = (const float*)d_in[9];
    const float* Wc2 = (const float*)d_in[10];
    const float* bc2 = (const float*)d_in[11];
    float* out = (float*)d_out;
    int* wsi = (int*)d_ws;
    const int n = in_sizes[0] / 3;
    const int nb = (n + 255) / 256;
    const int max_tiles = (n + TILE - 1) / TILE + NF - 1;  // worst-case grid

    k_count<<<nb, 256, 0, stream>>>(positions, centroids, n, wsi + 32);
    k_scan<<<1, 512, 0, stream>>>(wsi, nb);
    k_scatter<<<nb, 256, 0, stream>>>(positions, centroids, n, nb, wsi);
    k_main<<<max_tiles, 256, 0, stream>>>(positions, directions, app, Wd1, bd1, Wd2,
                                          bd2, Wc1, bc1, Wc2, bc2, wsi, nb, out);
}

// Round 5
// 248.390 us; speedup vs baseline: 15.4265x; 1.1869x over previous
//
#include <hip/hip_runtime.h>
#include <math.h>

#define NF 8
#define HID 128
#define NAPP 32
#define TILE 256   // points per k_main block (1 per thread)

typedef _Float16 h2 __attribute__((ext_vector_type(2)));
typedef unsigned int u32;

__device__ __forceinline__ float dot2a(h2 a, h2 b, float c) {
#if __has_builtin(__builtin_amdgcn_fdot2)
    return __builtin_amdgcn_fdot2(a, b, c, false);
#else
    return fmaf((float)a[0], (float)b[0], fmaf((float)a[1], (float)b[1], c));
#endif
}
__device__ __forceinline__ h2 as_h2(u32 x) { return __builtin_bit_cast(h2, x); }
__device__ __forceinline__ u32 pack_h2(float a, float b) {
    h2 v; v[0] = (_Float16)a; v[1] = (_Float16)b;
    return __builtin_bit_cast(u32, v);
}

// ws int layout:
//   [0..7] counts, [8..15] starts, [16..23] tile-prefix, [24] total tiles
//   [32 .. 32+NB*8) per-block counts -> write offsets;  [32+NB*8 ..) perm

__device__ __forceinline__ int assign_field(float px, float py, float pz,
                                            const float* __restrict__ cen) {
    int best = 0;
    float bd = 3.4e38f;
#pragma unroll
    for (int k = 0; k < NF; ++k) {
        float dx = px - cen[k * 3 + 0];
        float dy = py - cen[k * 3 + 1];
        float dz = pz - cen[k * 3 + 2];
        float d = fmaf(dx, dx, fmaf(dy, dy, dz * dz));
        if (d < bd) { bd = d; best = k; }
    }
    return best;
}

__global__ void k_count(const float* __restrict__ pos, const float* __restrict__ cen,
                        int n, int* __restrict__ blockcnt) {
    __shared__ int lc[NF];
    int tid = threadIdx.x;
    if (tid < NF) lc[tid] = 0;
    __syncthreads();
    int i = blockIdx.x * blockDim.x + tid;
    int lane = tid & 63;
    int f = -1;
    if (i < n) f = assign_field(pos[3 * i], pos[3 * i + 1], pos[3 * i + 2], cen);
#pragma unroll
    for (int k = 0; k < NF; ++k) {
        unsigned long long m = __ballot(f == k);
        if (m != 0ull && lane == __builtin_ctzll(m))
            atomicAdd(&lc[k], __builtin_popcountll(m));
    }
    __syncthreads();
    if (tid < NF) blockcnt[blockIdx.x * NF + tid] = lc[tid];
}

__global__ void k_scan(int* __restrict__ ws, int nb) {
    int f = threadIdx.x >> 6;
    int lane = threadIdx.x & 63;
    int* c = ws + 32;
    __shared__ int totals[NF];
    __shared__ int starts[NF];
    int tot = 0;
    for (int b = lane; b < nb; b += 64) tot += c[b * NF + f];
#pragma unroll
    for (int d = 1; d < 64; d <<= 1) tot += __shfl_xor(tot, d, 64);
    if (lane == 0) totals[f] = tot;
    __syncthreads();
    if (threadIdx.x == 0) {
        int s = 0, tp = 0;
        for (int k = 0; k < NF; ++k) {
            starts[k] = s;
            ws[k] = totals[k];
            ws[8 + k] = s;
            ws[16 + k] = tp;
            s += totals[k];
            tp += (totals[k] + TILE - 1) / TILE;
        }
        ws[24] = tp;
    }
    __syncthreads();
    int run = starts[f];
    for (int b0 = 0; b0 < nb; b0 += 64) {
        int b = b0 + lane;
        int v = (b < nb) ? c[b * NF + f] : 0;
        int inc = v;
#pragma unroll
        for (int d = 1; d < 64; d <<= 1) {
            int t = __shfl_up(inc, d, 64);
            if (lane >= d) inc += t;
        }
        if (b < nb) c[b * NF + f] = run + (inc - v);
        run += __shfl(inc, 63, 64);
    }
}

__global__ void k_scatter(const float* __restrict__ pos, const float* __restrict__ cen,
                          int n, int nb, int* __restrict__ ws) {
    __shared__ int cur[NF];
    int tid = threadIdx.x;
    int* gofs = ws + 32;
    int* perm = ws + 32 + nb * NF;
    if (tid < NF) cur[tid] = gofs[blockIdx.x * NF + tid];
    __syncthreads();
    int i = blockIdx.x * blockDim.x + tid;
    int lane = tid & 63;
    int f = -1;
    if (i < n) f = assign_field(pos[3 * i], pos[3 * i + 1], pos[3 * i + 2], cen);
#pragma unroll
    for (int k = 0; k < NF; ++k) {
        unsigned long long m = __ballot(f == k);
        if (f == k) {
            int leader = __builtin_ctzll(m);
            int base = 0;
            if (lane == leader) base = atomicAdd(&cur[k], __builtin_popcountll(m));
            base = __shfl(base, leader, 64);
            int rank = __builtin_popcountll(m & ((1ull << lane) - 1ull));
            perm[base + rank] = i;
        }
    }
}

// One block = one 256-point tile of one field; 1 point per thread.
// f16 weights packed as half2 K-pairs in LDS; v_dot2_f32_f16 main loops.
// All hot-loop LDS reads are wave-uniform (broadcast, conflict-free).
__global__ __launch_bounds__(256, 3) void k_main(
    const float* __restrict__ positions, const float* __restrict__ directions,
    const float* __restrict__ app,
    const float* __restrict__ Wd1, const float* __restrict__ bd1,
    const float* __restrict__ Wd2, const float* __restrict__ bd2,
    const float* __restrict__ Wc1, const float* __restrict__ bc1,
    const float* __restrict__ Wc2, const float* __restrict__ bc2,
    const int* __restrict__ ws, int nb, float* __restrict__ out) {
    const int b = blockIdx.x;
    if (b >= ws[24]) return;
    int f = 0;
#pragma unroll
    for (int k = 1; k < NF; ++k) if (b >= ws[16 + k]) f = k;
    const int tile = b - ws[16 + f];
    const int cnt = ws[f];
    const int start = ws[8 + f];
    const int* perm = ws + 32 + nb * NF;
    const int tid = threadIdx.x;

    __shared__ float sWd1p[HID * 4];   // {w0,w1,w2,bd1} per j, fp32   (2 KB)
    __shared__ float sBc1[HID];        // bc1 fp32                     (0.5 KB)
    __shared__ u32 sWd2h[64 * 16];     // [jp][o] = h2(Wd2[2jp][o],Wd2[2jp+1][o]) (4 KB)
    __shared__ u32 sWc1h[HID * 28];    // [j][kp] = h2(Wc1[2kp][j],Wc1[2kp+1][j]) (14 KB)
    __shared__ u32 sWc2h[64 * 4];      // [jp][ch] pairs, [jp][3]=0    (1 KB)
    __shared__ float sConst[20];       // [0..15]=bd2, [16..18]=bc2

    // ---- stage packed weights (once per block) ----
    if (tid < HID) {
        int j = tid;
        sWd1p[j * 4 + 0] = Wd1[f * 3 * HID + 0 * HID + j];
        sWd1p[j * 4 + 1] = Wd1[f * 3 * HID + 1 * HID + j];
        sWd1p[j * 4 + 2] = Wd1[f * 3 * HID + 2 * HID + j];
        sWd1p[j * 4 + 3] = bd1[f * HID + j];
        sBc1[j] = bc1[f * HID + j];
        for (int k = 0; k < 25; ++k) {
            float a = Wc1[f * 50 * HID + (2 * k) * HID + j];
            float c = Wc1[f * 50 * HID + (2 * k + 1) * HID + j];
            sWc1h[j * 28 + k] = pack_h2(a, c);
        }
        sWc1h[j * 28 + 25] = 0u;
        sWc1h[j * 28 + 26] = 0u;
        sWc1h[j * 28 + 27] = 0u;
    }
    {
        int jp = tid >> 2, og = (tid & 3) * 4;
        for (int t = 0; t < 4; ++t) {
            int o = og + t;
            float a = Wd2[f * HID * 16 + (2 * jp) * 16 + o];
            float c = Wd2[f * HID * 16 + (2 * jp + 1) * 16 + o];
            sWd2h[jp * 16 + o] = pack_h2(a, c);
        }
    }
    if (tid < 64) {
        int jp = tid;
        for (int ch = 0; ch < 3; ++ch) {
            float a = Wc2[f * HID * 3 + (2 * jp) * 3 + ch];
            float c = Wc2[f * HID * 3 + (2 * jp + 1) * 3 + ch];
            sWc2h[jp * 4 + ch] = pack_h2(a, c);
        }
        sWc2h[jp * 4 + 3] = 0u;
    }
    if (tid < 16) sConst[tid] = bd2[f * 16 + tid];
    else if (tid < 19) sConst[tid] = bc2[f * 3 + (tid - 16)];
    __syncthreads();

    // ---- one point per thread ----
    const int pl = tile * TILE + tid;
    const bool valid = (pl < cnt);
    const int idx = perm[start + (valid ? pl : cnt - 1)];

    const float px = positions[idx * 3 + 0];
    const float py = positions[idx * 3 + 1];
    const float pz = positions[idx * 3 + 2];
    h2 cinh[25];  // K-pairs of [dir(3), geo(15), app(32)]
    {
        float d0 = directions[idx * 3 + 0];
        float d1 = directions[idx * 3 + 1];
        float d2v = directions[idx * 3 + 2];
        cinh[0] = as_h2(pack_h2(d0, d1));
        cinh[1][0] = (_Float16)d2v;  // [1][1] = geo0, filled later
        const float4* ap = (const float4*)(app + idx * NAPP);
#pragma unroll
        for (int t = 0; t < 8; ++t) {
            float4 a = ap[t];
            cinh[9 + 2 * t] = as_h2(pack_h2(a.x, a.y));
            cinh[10 + 2 * t] = as_h2(pack_h2(a.z, a.w));
        }
    }

    // density MLP: 3 -> 128 (fp32) -> 16 (dot2)
    float dout[16];
#pragma unroll
    for (int o = 0; o < 16; ++o) dout[o] = sConst[o];
#pragma unroll 2
    for (int jp = 0; jp < 64; ++jp) {
        float4 w0 = *(const float4*)&sWd1p[(2 * jp) * 4];
        float4 w1 = *(const float4*)&sWd1p[(2 * jp + 1) * 4];
        float h0 = fmaxf(fmaf(pz, w0.z, fmaf(py, w0.y, fmaf(px, w0.x, w0.w))), 0.f);
        float h1 = fmaxf(fmaf(pz, w1.z, fmaf(py, w1.y, fmaf(px, w1.x, w1.w))), 0.f);
        h2 hp = as_h2(pack_h2(h0, h1));
        const uint4* wr = (const uint4*)&sWd2h[jp * 16];
        uint4 b0 = wr[0], b1 = wr[1], b2 = wr[2], b3 = wr[3];
        dout[0] = dot2a(hp, as_h2(b0.x), dout[0]);
        dout[1] = dot2a(hp, as_h2(b0.y), dout[1]);
        dout[2] = dot2a(hp, as_h2(b0.z), dout[2]);
        dout[3] = dot2a(hp, as_h2(b0.w), dout[3]);
        dout[4] = dot2a(hp, as_h2(b1.x), dout[4]);
        dout[5] = dot2a(hp, as_h2(b1.y), dout[5]);
        dout[6] = dot2a(hp, as_h2(b1.z), dout[6]);
        dout[7] = dot2a(hp, as_h2(b1.w), dout[7]);
        dout[8] = dot2a(hp, as_h2(b2.x), dout[8]);
        dout[9] = dot2a(hp, as_h2(b2.y), dout[9]);
        dout[10] = dot2a(hp, as_h2(b2.z), dout[10]);
        dout[11] = dot2a(hp, as_h2(b2.w), dout[11]);
        dout[12] = dot2a(hp, as_h2(b3.x), dout[12]);
        dout[13] = dot2a(hp, as_h2(b3.y), dout[13]);
        dout[14] = dot2a(hp, as_h2(b3.z), dout[14]);
        dout[15] = dot2a(hp, as_h2(b3.w), dout[15]);
    }
    const float dens = __expf(dout[0]);
    // geo -> cin k=3..17
    cinh[1][1] = (_Float16)dout[1];
#pragma unroll
    for (int g = 0; g < 7; ++g)
        cinh[2 + g] = as_h2(pack_h2(dout[2 + 2 * g], dout[3 + 2 * g]));

    // color MLP: 50 -> 128 -> 3
    float r0 = sConst[16], r1 = sConst[17], r2 = sConst[18];
#pragma unroll 2
    for (int jp = 0; jp < 64; ++jp) {
        const uint4* ra = (const uint4*)&sWc1h[(2 * jp) * 28];
        const uint4* rb = (const uint4*)&sWc1h[(2 * jp + 1) * 28];
        float acc0 = sBc1[2 * jp];
        float acc1 = sBc1[2 * jp + 1];
#pragma unroll
        for (int q = 0; q < 7; ++q) {
            uint4 ua = ra[q];
            uint4 ub = rb[q];
            acc0 = dot2a(cinh[4 * q + 0], as_h2(ua.x), acc0);
            acc1 = dot2a(cinh[4 * q + 0], as_h2(ub.x), acc1);
            if (4 * q + 1 < 25) {
                acc0 = dot2a(cinh[4 * q + 1], as_h2(ua.y), acc0);
                acc1 = dot2a(cinh[4 * q + 1], as_h2(ub.y), acc1);
            }
            if (4 * q + 2 < 25) {
                acc0 = dot2a(cinh[4 * q + 2], as_h2(ua.z), acc0);
                acc1 = dot2a(cinh[4 * q + 2], as_h2(ub.z), acc1);
            }
            if (4 * q + 3 < 25) {
                acc0 = dot2a(cinh[4 * q + 3], as_h2(ua.w), acc0);
                acc1 = dot2a(cinh[4 * q + 3], as_h2(ub.w), acc1);
            }
        }
        float hc0 = fmaxf(acc0, 0.f);
        float hc1 = fmaxf(acc1, 0.f);
        h2 hcp = as_h2(pack_h2(hc0, hc1));
        const uint4 cw = ((const uint4*)sWc2h)[jp];
        r0 = dot2a(hcp, as_h2(cw.x), r0);
        r1 = dot2a(hcp, as_h2(cw.y), r1);
        r2 = dot2a(hcp, as_h2(cw.z), r2);
    }

    if (valid) {
        float4 o4;
        o4.x = dens;
        o4.y = 1.f / (1.f + __expf(-r0));
        o4.z = 1.f / (1.f + __expf(-r1));
        o4.w = 1.f / (1.f + __expf(-r2));
        *(float4*)&out[idx * 4] = o4;
    }
}

extern "C" void kernel_launch(void* const* d_in, const int* in_sizes, int n_in,
                              void* d_out, int out_size, void* d_ws, size_t ws_size,
                              hipStream_t stream) {
    const float* positions = (const float*)d_in[0];
    const float* directions = (const float*)d_in[1];
    const float* app = (const float*)d_in[2];
    const float* centroids = (const float*)d_in[3];
    const float* Wd1 = (const float*)d_in[4];
    const float* bd1 = (const float*)d_in[5];
    const float* Wd2 = (const float*)d_in[6];
    const float* bd2 = (const float*)d_in[7];
    const float* Wc1 = (const float*)d_in[8];
    const float* bc1 = (const float*)d_in[9];
    const float* Wc2 = (const float*)d_in[10];
    const float* bc2 = (const float*)d_in[11];
    float* out = (float*)d_out;
    int* wsi = (int*)d_ws;
    const int n = in_sizes[0] / 3;
    const int nb = (n + 255) / 256;
    const int max_tiles = (n + TILE - 1) / TILE + NF - 1;

    k_count<<<nb, 256, 0, stream>>>(positions, centroids, n, wsi + 32);
    k_scan<<<1, 512, 0, stream>>>(wsi, nb);
    k_scatter<<<nb, 256, 0, stream>>>(positions, centroids, n, nb, wsi);
    k_main<<<max_tiles, 256, 0, stream>>>(positions, directions, app, Wd1, bd1, Wd2,
                                          bd2, Wc1, bc1, Wc2, bc2, wsi, nb, out);
}

// Round 6
// 233.586 us; speedup vs baseline: 16.4042x; 1.0634x over previous
//
#include <hip/hip_runtime.h>
#include <math.h>

#define NF 8
#define HID 128
#define NAPP 32
#define TILE 512   // points per k_main block (2 per thread)

typedef _Float16 h2 __attribute__((ext_vector_type(2)));
typedef unsigned int u32;

__device__ __forceinline__ float dot2a(h2 a, h2 b, float c) {
#if __has_builtin(__builtin_amdgcn_fdot2)
    return __builtin_amdgcn_fdot2(a, b, c, false);
#else
    return fmaf((float)a[0], (float)b[0], fmaf((float)a[1], (float)b[1], c));
#endif
}
__device__ __forceinline__ h2 as_h2(u32 x) { return __builtin_bit_cast(h2, x); }
__device__ __forceinline__ u32 pack_h2(float a, float b) {
    h2 v; v[0] = (_Float16)a; v[1] = (_Float16)b;
    return __builtin_bit_cast(u32, v);
}

// ws int layout:
//   [0..7] counts, [8..15] starts, [16..23] tile-prefix, [24] total tiles
//   [32 .. 32+NB4*8) per-block counts -> write offsets;  [32+NB4*8 ..) perm

__device__ __forceinline__ int assign_field(float px, float py, float pz,
                                            const float* __restrict__ cen) {
    int best = 0;
    float bd = 3.4e38f;
#pragma unroll
    for (int k = 0; k < NF; ++k) {
        float dx = px - cen[k * 3 + 0];
        float dy = py - cen[k * 3 + 1];
        float dz = pz - cen[k * 3 + 2];
        float d = fmaf(dx, dx, fmaf(dy, dy, dz * dz));
        if (d < bd) { bd = d; best = k; }
    }
    return best;
}

// 4 points per thread, float4 loads, LDS histogram.
__global__ void k_count(const float* __restrict__ pos, const float* __restrict__ cen,
                        int n, int* __restrict__ blockcnt) {
    __shared__ int lc[NF];
    int tid = threadIdx.x;
    if (tid < NF) lc[tid] = 0;
    __syncthreads();
    int i4 = blockIdx.x * blockDim.x + tid;
    int base = i4 * 4;
    if (base + 3 < n) {
        const float4* p4 = (const float4*)pos;
        float4 a = p4[i4 * 3 + 0];
        float4 b = p4[i4 * 3 + 1];
        float4 c = p4[i4 * 3 + 2];
        atomicAdd(&lc[assign_field(a.x, a.y, a.z, cen)], 1);
        atomicAdd(&lc[assign_field(a.w, b.x, b.y, cen)], 1);
        atomicAdd(&lc[assign_field(b.z, b.w, c.x, cen)], 1);
        atomicAdd(&lc[assign_field(c.y, c.z, c.w, cen)], 1);
    } else {
        for (int i = base; i < n; ++i)
            atomicAdd(&lc[assign_field(pos[3 * i], pos[3 * i + 1], pos[3 * i + 2], cen)], 1);
    }
    __syncthreads();
    if (tid < NF) blockcnt[blockIdx.x * NF + tid] = lc[tid];
}

// One block, 512 threads = 8 waves; wave w owns field w.
__global__ void k_scan(int* __restrict__ ws, int nb4) {
    int f = threadIdx.x >> 6;
    int lane = threadIdx.x & 63;
    int* c = ws + 32;
    __shared__ int totals[NF];
    __shared__ int starts[NF];
    int tot = 0;
    for (int b = lane; b < nb4; b += 64) tot += c[b * NF + f];
#pragma unroll
    for (int d = 1; d < 64; d <<= 1) tot += __shfl_xor(tot, d, 64);
    if (lane == 0) totals[f] = tot;
    __syncthreads();
    if (threadIdx.x == 0) {
        int s = 0, tp = 0;
        for (int k = 0; k < NF; ++k) {
            starts[k] = s;
            ws[k] = totals[k];
            ws[8 + k] = s;
            ws[16 + k] = tp;
            s += totals[k];
            tp += (totals[k] + TILE - 1) / TILE;
        }
        ws[24] = tp;
    }
    __syncthreads();
    int run = starts[f];
    for (int b0 = 0; b0 < nb4; b0 += 64) {
        int b = b0 + lane;
        int v = (b < nb4) ? c[b * NF + f] : 0;
        int inc = v;
#pragma unroll
        for (int d = 1; d < 64; d <<= 1) {
            int t = __shfl_up(inc, d, 64);
            if (lane >= d) inc += t;
        }
        if (b < nb4) c[b * NF + f] = run + (inc - v);
        run += __shfl(inc, 63, 64);
    }
}

// 4 points per thread; LDS cursors (order within a field is arbitrary).
__global__ void k_scatter(const float* __restrict__ pos, const float* __restrict__ cen,
                          int n, int nb4, int* __restrict__ ws) {
    __shared__ int cur[NF];
    int tid = threadIdx.x;
    int* gofs = ws + 32;
    int* perm = ws + 32 + nb4 * NF;
    if (tid < NF) cur[tid] = gofs[blockIdx.x * NF + tid];
    __syncthreads();
    int i4 = blockIdx.x * blockDim.x + tid;
    int base = i4 * 4;
    if (base + 3 < n) {
        const float4* p4 = (const float4*)pos;
        float4 a = p4[i4 * 3 + 0];
        float4 b = p4[i4 * 3 + 1];
        float4 c = p4[i4 * 3 + 2];
        int f0 = assign_field(a.x, a.y, a.z, cen);
        int f1 = assign_field(a.w, b.x, b.y, cen);
        int f2 = assign_field(b.z, b.w, c.x, cen);
        int f3 = assign_field(c.y, c.z, c.w, cen);
        perm[atomicAdd(&cur[f0], 1)] = base;
        perm[atomicAdd(&cur[f1], 1)] = base + 1;
        perm[atomicAdd(&cur[f2], 1)] = base + 2;
        perm[atomicAdd(&cur[f3], 1)] = base + 3;
    } else {
        for (int i = base; i < n; ++i) {
            int f = assign_field(pos[3 * i], pos[3 * i + 1], pos[3 * i + 2], cen);
            perm[atomicAdd(&cur[f], 1)] = i;
        }
    }
}

// One block = one 512-point tile of one field; 2 points per thread.
// f16 weights in LDS (half2 K-pairs), broadcast reads shared by both points.
__global__ __launch_bounds__(256, 2) void k_main(
    const float* __restrict__ positions, const float* __restrict__ directions,
    const float* __restrict__ app,
    const float* __restrict__ Wd1, const float* __restrict__ bd1,
    const float* __restrict__ Wd2, const float* __restrict__ bd2,
    const float* __restrict__ Wc1, const float* __restrict__ bc1,
    const float* __restrict__ Wc2, const float* __restrict__ bc2,
    const int* __restrict__ ws, int nb4, float* __restrict__ out) {
    const int b = blockIdx.x;
    if (b >= ws[24]) return;
    int f = 0;
#pragma unroll
    for (int k = 1; k < NF; ++k) if (b >= ws[16 + k]) f = k;
    const int tile = b - ws[16 + f];
    const int cnt = ws[f];
    const int start = ws[8 + f];
    const int* perm = ws + 32 + nb4 * NF;
    const int tid = threadIdx.x;

    __shared__ float sWd1p[HID * 4];   // {w0,w1,w2,bd1} per j, fp32
    __shared__ float sBc1[HID];        // bc1 fp32
    __shared__ u32 sWd2h[64 * 16];     // [jp][o] = h2(Wd2[2jp][o],Wd2[2jp+1][o])
    __shared__ u32 sWc1h[HID * 28];    // [j][kp] = h2(Wc1[2kp][j],Wc1[2kp+1][j])
    __shared__ u32 sWc2h[64 * 4];      // [jp][ch] pairs, [jp][3]=0
    __shared__ float sConst[20];       // [0..15]=bd2, [16..18]=bc2

    if (tid < HID) {
        int j = tid;
        sWd1p[j * 4 + 0] = Wd1[f * 3 * HID + 0 * HID + j];
        sWd1p[j * 4 + 1] = Wd1[f * 3 * HID + 1 * HID + j];
        sWd1p[j * 4 + 2] = Wd1[f * 3 * HID + 2 * HID + j];
        sWd1p[j * 4 + 3] = bd1[f * HID + j];
        sBc1[j] = bc1[f * HID + j];
        for (int k = 0; k < 25; ++k) {
            float a = Wc1[f * 50 * HID + (2 * k) * HID + j];
            float c = Wc1[f * 50 * HID + (2 * k + 1) * HID + j];
            sWc1h[j * 28 + k] = pack_h2(a, c);
        }
        sWc1h[j * 28 + 25] = 0u;
        sWc1h[j * 28 + 26] = 0u;
        sWc1h[j * 28 + 27] = 0u;
    }
    {
        int jp = tid >> 2, og = (tid & 3) * 4;
        for (int t = 0; t < 4; ++t) {
            int o = og + t;
            float a = Wd2[f * HID * 16 + (2 * jp) * 16 + o];
            float c = Wd2[f * HID * 16 + (2 * jp + 1) * 16 + o];
            sWd2h[jp * 16 + o] = pack_h2(a, c);
        }
    }
    if (tid < 64) {
        int jp = tid;
        for (int ch = 0; ch < 3; ++ch) {
            float a = Wc2[f * HID * 3 + (2 * jp) * 3 + ch];
            float c = Wc2[f * HID * 3 + (2 * jp + 1) * 3 + ch];
            sWc2h[jp * 4 + ch] = pack_h2(a, c);
        }
        sWc2h[jp * 4 + 3] = 0u;
    }
    if (tid < 16) sConst[tid] = bd2[f * 16 + tid];
    else if (tid < 19) sConst[tid] = bc2[f * 3 + (tid - 16)];
    __syncthreads();

    // ---- two points per thread ----
    const int pl0 = tile * TILE + tid;
    const int pl1 = pl0 + 256;
    const bool v0 = (pl0 < cnt);
    const bool v1 = (pl1 < cnt);
    const int idx0 = perm[start + (v0 ? pl0 : cnt - 1)];
    const int idx1 = perm[start + (v1 ? pl1 : cnt - 1)];

    const float px0 = positions[idx0 * 3 + 0];
    const float py0 = positions[idx0 * 3 + 1];
    const float pz0 = positions[idx0 * 3 + 2];
    const float px1 = positions[idx1 * 3 + 0];
    const float py1 = positions[idx1 * 3 + 1];
    const float pz1 = positions[idx1 * 3 + 2];
    h2 cin0[25], cin1[25];
    {
        cin0[0] = as_h2(pack_h2(directions[idx0 * 3 + 0], directions[idx0 * 3 + 1]));
        cin0[1][0] = (_Float16)directions[idx0 * 3 + 2];
        cin1[0] = as_h2(pack_h2(directions[idx1 * 3 + 0], directions[idx1 * 3 + 1]));
        cin1[1][0] = (_Float16)directions[idx1 * 3 + 2];
        const float4* ap0 = (const float4*)(app + idx0 * NAPP);
        const float4* ap1 = (const float4*)(app + idx1 * NAPP);
#pragma unroll
        for (int t = 0; t < 8; ++t) {
            float4 a = ap0[t];
            cin0[9 + 2 * t] = as_h2(pack_h2(a.x, a.y));
            cin0[10 + 2 * t] = as_h2(pack_h2(a.z, a.w));
            float4 c = ap1[t];
            cin1[9 + 2 * t] = as_h2(pack_h2(c.x, c.y));
            cin1[10 + 2 * t] = as_h2(pack_h2(c.z, c.w));
        }
    }

    // density MLP: 3 -> 128 (fp32) -> 16 (dot2), both points share weight reads
    float dout0[16], dout1[16];
#pragma unroll
    for (int o = 0; o < 16; ++o) { dout0[o] = sConst[o]; dout1[o] = sConst[o]; }
#pragma unroll 1
    for (int jp = 0; jp < 64; ++jp) {
        float4 w0 = *(const float4*)&sWd1p[(2 * jp) * 4];
        float4 w1 = *(const float4*)&sWd1p[(2 * jp + 1) * 4];
        float h00 = fmaxf(fmaf(pz0, w0.z, fmaf(py0, w0.y, fmaf(px0, w0.x, w0.w))), 0.f);
        float h01 = fmaxf(fmaf(pz0, w1.z, fmaf(py0, w1.y, fmaf(px0, w1.x, w1.w))), 0.f);
        float h10 = fmaxf(fmaf(pz1, w0.z, fmaf(py1, w0.y, fmaf(px1, w0.x, w0.w))), 0.f);
        float h11 = fmaxf(fmaf(pz1, w1.z, fmaf(py1, w1.y, fmaf(px1, w1.x, w1.w))), 0.f);
        h2 hp0 = as_h2(pack_h2(h00, h01));
        h2 hp1 = as_h2(pack_h2(h10, h11));
        const uint4* wr = (const uint4*)&sWd2h[jp * 16];
        uint4 b0 = wr[0], b1 = wr[1], b2 = wr[2], b3 = wr[3];
        dout0[0] = dot2a(hp0, as_h2(b0.x), dout0[0]);   dout1[0] = dot2a(hp1, as_h2(b0.x), dout1[0]);
        dout0[1] = dot2a(hp0, as_h2(b0.y), dout0[1]);   dout1[1] = dot2a(hp1, as_h2(b0.y), dout1[1]);
        dout0[2] = dot2a(hp0, as_h2(b0.z), dout0[2]);   dout1[2] = dot2a(hp1, as_h2(b0.z), dout1[2]);
        dout0[3] = dot2a(hp0, as_h2(b0.w), dout0[3]);   dout1[3] = dot2a(hp1, as_h2(b0.w), dout1[3]);
        dout0[4] = dot2a(hp0, as_h2(b1.x), dout0[4]);   dout1[4] = dot2a(hp1, as_h2(b1.x), dout1[4]);
        dout0[5] = dot2a(hp0, as_h2(b1.y), dout0[5]);   dout1[5] = dot2a(hp1, as_h2(b1.y), dout1[5]);
        dout0[6] = dot2a(hp0, as_h2(b1.z), dout0[6]);   dout1[6] = dot2a(hp1, as_h2(b1.z), dout1[6]);
        dout0[7] = dot2a(hp0, as_h2(b1.w), dout0[7]);   dout1[7] = dot2a(hp1, as_h2(b1.w), dout1[7]);
        dout0[8] = dot2a(hp0, as_h2(b2.x), dout0[8]);   dout1[8] = dot2a(hp1, as_h2(b2.x), dout1[8]);
        dout0[9] = dot2a(hp0, as_h2(b2.y), dout0[9]);   dout1[9] = dot2a(hp1, as_h2(b2.y), dout1[9]);
        dout0[10] = dot2a(hp0, as_h2(b2.z), dout0[10]); dout1[10] = dot2a(hp1, as_h2(b2.z), dout1[10]);
        dout0[11] = dot2a(hp0, as_h2(b2.w), dout0[11]); dout1[11] = dot2a(hp1, as_h2(b2.w), dout1[11]);
        dout0[12] = dot2a(hp0, as_h2(b3.x), dout0[12]); dout1[12] = dot2a(hp1, as_h2(b3.x), dout1[12]);
        dout0[13] = dot2a(hp0, as_h2(b3.y), dout0[13]); dout1[13] = dot2a(hp1, as_h2(b3.y), dout1[13]);
        dout0[14] = dot2a(hp0, as_h2(b3.z), dout0[14]); dout1[14] = dot2a(hp1, as_h2(b3.z), dout1[14]);
        dout0[15] = dot2a(hp0, as_h2(b3.w), dout0[15]); dout1[15] = dot2a(hp1, as_h2(b3.w), dout1[15]);
    }
    const float dens0 = __expf(dout0[0]);
    const float dens1 = __expf(dout1[0]);
    cin0[1][1] = (_Float16)dout0[1];
    cin1[1][1] = (_Float16)dout1[1];
#pragma unroll
    for (int g = 0; g < 7; ++g) {
        cin0[2 + g] = as_h2(pack_h2(dout0[2 + 2 * g], dout0[3 + 2 * g]));
        cin1[2 + g] = as_h2(pack_h2(dout1[2 + 2 * g], dout1[3 + 2 * g]));
    }

    // color MLP: 50 -> 128 -> 3, both points share weight reads
    float r00 = sConst[16], r01 = sConst[17], r02 = sConst[18];
    float r10 = sConst[16], r11 = sConst[17], r12 = sConst[18];
#pragma unroll 1
    for (int jp = 0; jp < 64; ++jp) {
        const uint4* ra = (const uint4*)&sWc1h[(2 * jp) * 28];
        const uint4* rb = (const uint4*)&sWc1h[(2 * jp + 1) * 28];
        float a0 = sBc1[2 * jp], a1 = sBc1[2 * jp + 1];
        float b0 = a0, b1 = a1;
#pragma unroll
        for (int q = 0; q < 7; ++q) {
            uint4 ua = ra[q];
            uint4 ub = rb[q];
            a0 = dot2a(cin0[4 * q + 0], as_h2(ua.x), a0);
            a1 = dot2a(cin0[4 * q + 0], as_h2(ub.x), a1);
            b0 = dot2a(cin1[4 * q + 0], as_h2(ua.x), b0);
            b1 = dot2a(cin1[4 * q + 0], as_h2(ub.x), b1);
            if (4 * q + 1 < 25) {
                a0 = dot2a(cin0[4 * q + 1], as_h2(ua.y), a0);
                a1 = dot2a(cin0[4 * q + 1], as_h2(ub.y), a1);
                b0 = dot2a(cin1[4 * q + 1], as_h2(ua.y), b0);
                b1 = dot2a(cin1[4 * q + 1], as_h2(ub.y), b1);
            }
            if (4 * q + 2 < 25) {
                a0 = dot2a(cin0[4 * q + 2], as_h2(ua.z), a0);
                a1 = dot2a(cin0[4 * q + 2], as_h2(ub.z), a1);
                b0 = dot2a(cin1[4 * q + 2], as_h2(ua.z), b0);
                b1 = dot2a(cin1[4 * q + 2], as_h2(ub.z), b1);
            }
            if (4 * q + 3 < 25) {
                a0 = dot2a(cin0[4 * q + 3], as_h2(ua.w), a0);
                a1 = dot2a(cin0[4 * q + 3], as_h2(ub.w), a1);
                b0 = dot2a(cin1[4 * q + 3], as_h2(ua.w), b0);
                b1 = dot2a(cin1[4 * q + 3], as_h2(ub.w), b1);
            }
        }
        h2 hcp0 = as_h2(pack_h2(fmaxf(a0, 0.f), fmaxf(a1, 0.f)));
        h2 hcp1 = as_h2(pack_h2(fmaxf(b0, 0.f), fmaxf(b1, 0.f)));
        const uint4 cw = ((const uint4*)sWc2h)[jp];
        r00 = dot2a(hcp0, as_h2(cw.x), r00);  r10 = dot2a(hcp1, as_h2(cw.x), r10);
        r01 = dot2a(hcp0, as_h2(cw.y), r01);  r11 = dot2a(hcp1, as_h2(cw.y), r11);
        r02 = dot2a(hcp0, as_h2(cw.z), r02);  r12 = dot2a(hcp1, as_h2(cw.z), r12);
    }

    if (v0) {
        float4 o4;
        o4.x = dens0;
        o4.y = 1.f / (1.f + __expf(-r00));
        o4.z = 1.f / (1.f + __expf(-r01));
        o4.w = 1.f / (1.f + __expf(-r02));
        *(float4*)&out[idx0 * 4] = o4;
    }
    if (v1) {
        float4 o5;
        o5.x = dens1;
        o5.y = 1.f / (1.f + __expf(-r10));
        o5.z = 1.f / (1.f + __expf(-r11));
        o5.w = 1.f / (1.f + __expf(-r12));
        *(float4*)&out[idx1 * 4] = o5;
    }
}

extern "C" void kernel_launch(void* const* d_in, const int* in_sizes, int n_in,
                              void* d_out, int out_size, void* d_ws, size_t ws_size,
                              hipStream_t stream) {
    const float* positions = (const float*)d_in[0];
    const float* directions = (const float*)d_in[1];
    const float* app = (const float*)d_in[2];
    const float* centroids = (const float*)d_in[3];
    const float* Wd1 = (const float*)d_in[4];
    const float* bd1 = (const float*)d_in[5];
    const float* Wd2 = (const float*)d_in[6];
    const float* bd2 = (const float*)d_in[7];
    const float* Wc1 = (const float*)d_in[8];
    const float* bc1 = (const float*)d_in[9];
    const float* Wc2 = (const float*)d_in[10];
    const float* bc2 = (const float*)d_in[11];
    float* out = (float*)d_out;
    int* wsi = (int*)d_ws;
    const int n = in_sizes[0] / 3;
    const int nb4 = (n + 1023) / 1024;   // 4 pts/thread, 256 threads
    const int max_tiles = (n + TILE - 1) / TILE + NF - 1;

    k_count<<<nb4, 256, 0, stream>>>(positions, centroids, n, wsi + 32);
    k_scan<<<1, 512, 0, stream>>>(wsi, nb4);
    k_scatter<<<nb4, 256, 0, stream>>>(positions, centroids, n, nb4, wsi);
    k_main<<<max_tiles, 256, 0, stream>>>(positions, directions, app, Wd1, bd1, Wd2,
                                          bd2, Wc1, bc1, Wc2, bc2, wsi, nb4, out);
}

// Round 7
// 199.688 us; speedup vs baseline: 19.1888x; 1.1698x over previous
//
#include <hip/hip_runtime.h>
#include <math.h>

#define NF 8
#define HID 128
#define TILE 512   // points per k_main block (4 waves x 8 iters x 16 pts)

typedef _Float16 f16;
typedef _Float16 h2 __attribute__((ext_vector_type(2)));
typedef _Float16 f16x8 __attribute__((ext_vector_type(8)));
typedef float f32x4 __attribute__((ext_vector_type(4)));
typedef unsigned int u32;
typedef u32 u32x2 __attribute__((ext_vector_type(2)));
typedef u32 u32x4 __attribute__((ext_vector_type(4)));

__device__ __forceinline__ u32 pk(float a, float b) {
    return __builtin_bit_cast(u32, __builtin_amdgcn_cvt_pkrtz(a, b));
}
__device__ __forceinline__ float dot2a(u32 a, u32 b, float c) {
    return __builtin_amdgcn_fdot2(__builtin_bit_cast(h2, a),
                                  __builtin_bit_cast(h2, b), c, false);
}
__device__ __forceinline__ void lfence() {
    asm volatile("s_waitcnt lgkmcnt(0)" ::: "memory");
}

// ws int layout:
//   [0..7] counts, [8..15] starts, [16..23] tile-prefix, [24] total tiles
//   [32 .. 32+NB4*8) per-block counts -> write offsets;  [32+NB4*8 ..) perm

__device__ __forceinline__ int assign_field(float px, float py, float pz,
                                            const float* __restrict__ cen) {
    int best = 0;
    float bd = 3.4e38f;
#pragma unroll
    for (int k = 0; k < NF; ++k) {
        float dx = px - cen[k * 3 + 0];
        float dy = py - cen[k * 3 + 1];
        float dz = pz - cen[k * 3 + 2];
        float d = fmaf(dx, dx, fmaf(dy, dy, dz * dz));
        if (d < bd) { bd = d; best = k; }
    }
    return best;
}

__global__ void k_count(const float* __restrict__ pos, const float* __restrict__ cen,
                        int n, int* __restrict__ blockcnt) {
    __shared__ int lc[NF];
    int tid = threadIdx.x;
    if (tid < NF) lc[tid] = 0;
    __syncthreads();
    int i4 = blockIdx.x * blockDim.x + tid;
    int base = i4 * 4;
    if (base + 3 < n) {
        const float4* p4 = (const float4*)pos;
        float4 a = p4[i4 * 3 + 0];
        float4 b = p4[i4 * 3 + 1];
        float4 c = p4[i4 * 3 + 2];
        atomicAdd(&lc[assign_field(a.x, a.y, a.z, cen)], 1);
        atomicAdd(&lc[assign_field(a.w, b.x, b.y, cen)], 1);
        atomicAdd(&lc[assign_field(b.z, b.w, c.x, cen)], 1);
        atomicAdd(&lc[assign_field(c.y, c.z, c.w, cen)], 1);
    } else {
        for (int i = base; i < n; ++i)
            atomicAdd(&lc[assign_field(pos[3 * i], pos[3 * i + 1], pos[3 * i + 2], cen)], 1);
    }
    __syncthreads();
    if (tid < NF) blockcnt[blockIdx.x * NF + tid] = lc[tid];
}

__global__ void k_scan(int* __restrict__ ws, int nb4) {
    int f = threadIdx.x >> 6;
    int lane = threadIdx.x & 63;
    int* c = ws + 32;
    __shared__ int totals[NF];
    __shared__ int starts[NF];
    int tot = 0;
    for (int b = lane; b < nb4; b += 64) tot += c[b * NF + f];
#pragma unroll
    for (int d = 1; d < 64; d <<= 1) tot += __shfl_xor(tot, d, 64);
    if (lane == 0) totals[f] = tot;
    __syncthreads();
    if (threadIdx.x == 0) {
        int s = 0, tp = 0;
        for (int k = 0; k < NF; ++k) {
            starts[k] = s;
            ws[k] = totals[k];
            ws[8 + k] = s;
            ws[16 + k] = tp;
            s += totals[k];
            tp += (totals[k] + TILE - 1) / TILE;
        }
        ws[24] = tp;
    }
    __syncthreads();
    int run = starts[f];
    for (int b0 = 0; b0 < nb4; b0 += 64) {
        int b = b0 + lane;
        int v = (b < nb4) ? c[b * NF + f] : 0;
        int inc = v;
#pragma unroll
        for (int d = 1; d < 64; d <<= 1) {
            int t = __shfl_up(inc, d, 64);
            if (lane >= d) inc += t;
        }
        if (b < nb4) c[b * NF + f] = run + (inc - v);
        run += __shfl(inc, 63, 64);
    }
}

__global__ void k_scatter(const float* __restrict__ pos, const float* __restrict__ cen,
                          int n, int nb4, int* __restrict__ ws) {
    __shared__ int cur[NF];
    int tid = threadIdx.x;
    int* gofs = ws + 32;
    int* perm = ws + 32 + nb4 * NF;
    if (tid < NF) cur[tid] = gofs[blockIdx.x * NF + tid];
    __syncthreads();
    int i4 = blockIdx.x * blockDim.x + tid;
    int base = i4 * 4;
    if (base + 3 < n) {
        const float4* p4 = (const float4*)pos;
        float4 a = p4[i4 * 3 + 0];
        float4 b = p4[i4 * 3 + 1];
        float4 c = p4[i4 * 3 + 2];
        int f0 = assign_field(a.x, a.y, a.z, cen);
        int f1 = assign_field(a.w, b.x, b.y, cen);
        int f2 = assign_field(b.z, b.w, c.x, cen);
        int f3 = assign_field(c.y, c.z, c.w, cen);
        perm[atomicAdd(&cur[f0], 1)] = base;
        perm[atomicAdd(&cur[f1], 1)] = base + 1;
        perm[atomicAdd(&cur[f2], 1)] = base + 2;
        perm[atomicAdd(&cur[f3], 1)] = base + 3;
    } else {
        for (int i = base; i < n; ++i) {
            int f = assign_field(pos[3 * i], pos[3 * i + 1], pos[3 * i + 2], cen);
            perm[atomicAdd(&cur[f], 1)] = i;
        }
    }
}

// MFMA k_main: one wave processes 16 points per iteration.
// cin layout per point (72 halves): [0..2]=dir, [3]=1(bias), [4..7]=0,
// [8..39]=app, [40..54]=geo, [55..63]=0. Wc1^T staged to match.
__global__ __launch_bounds__(256, 2) void k_main(
    const float* __restrict__ positions, const float* __restrict__ directions,
    const float* __restrict__ app,
    const float* __restrict__ Wd1, const float* __restrict__ bd1,
    const float* __restrict__ Wd2, const float* __restrict__ bd2,
    const float* __restrict__ Wc1, const float* __restrict__ bc1,
    const float* __restrict__ Wc2, const float* __restrict__ bc2,
    const int* __restrict__ ws, int nb4, float* __restrict__ out) {
    const int b = blockIdx.x;
    if (b >= ws[24]) return;
    int f = 0;
#pragma unroll
    for (int k = 1; k < NF; ++k) if (b >= ws[16 + k]) f = k;
    const int tile = b - ws[16 + f];
    const int cnt = ws[f];
    const int start = ws[8 + f];
    const int* perm = ws + 32 + nb4 * NF;
    const int tid = threadIdx.x;
    const int w = tid >> 6, lane = tid & 63;
    const int pt = lane & 15, quad = lane >> 4;

    __shared__ __align__(16) f16 sWc1t[HID * 72];   // [h][72] permuted    18 KB
    __shared__ __align__(16) u32 sWc2p[64 * 4];     // [hp][ch] h2 pairs    1 KB
    __shared__ __align__(16) float sPos[4][16 * 4]; // per-wave             1 KB
    __shared__ __align__(16) int sIdx[4][16];
    __shared__ __align__(16) f16 sCin[4][16 * 72];  // per-wave             9 KB
    __shared__ __align__(16) f16 sH[4][16 * 136];   // per-wave            17 KB

    // ---- stage Wc1^T (permuted, f16) and Wc2 pairs ----
    if (tid < HID) {
        int h = tid;
        f16* row = &sWc1t[h * 72];
        const float* Wf = Wc1 + f * 50 * HID;
        row[0] = (f16)Wf[0 * HID + h];
        row[1] = (f16)Wf[1 * HID + h];
        row[2] = (f16)Wf[2 * HID + h];
        row[3] = (f16)bc1[f * HID + h];
        row[4] = 0; row[5] = 0; row[6] = 0; row[7] = 0;
        for (int a = 0; a < 32; ++a) row[8 + a] = (f16)Wf[(18 + a) * HID + h];
        for (int g = 0; g < 15; ++g) row[40 + g] = (f16)Wf[(3 + g) * HID + h];
        for (int z = 55; z < 72; ++z) row[z] = 0;
    }
    if (tid < 64) {
        int hp = tid;
        const float* W2 = Wc2 + f * HID * 3;
        sWc2p[hp * 4 + 0] = pk(W2[(2 * hp) * 3 + 0], W2[(2 * hp + 1) * 3 + 0]);
        sWc2p[hp * 4 + 1] = pk(W2[(2 * hp) * 3 + 1], W2[(2 * hp + 1) * 3 + 1]);
        sWc2p[hp * 4 + 2] = pk(W2[(2 * hp) * 3 + 2], W2[(2 * hp + 1) * 3 + 2]);
        sWc2p[hp * 4 + 3] = 0;
    }
    if (lane < 16) {  // zero cin pad zones (per-wave region)
        f16* row = &sCin[w][pt * 72];
        u32x2 z2; z2.x = 0; z2.y = 0;
        *(u32x2*)&row[4] = z2;
        row[55] = 0;
        u32x4 z4; z4.x = 0; z4.y = 0; z4.z = 0; z4.w = 0;
        *(u32x4*)&row[56] = z4;
    }

    // ---- resident fragments (from global) ----
    u32 wd1a0[8], wd1a1[8];
    if (quad == 0) {
        const float* W1 = Wd1 + f * 3 * HID;
        const float* B1 = bd1 + f * HID;
#pragma unroll
        for (int mt = 0; mt < 8; ++mt) {
            int m = 16 * mt + pt;
            wd1a0[mt] = pk(W1[m], W1[HID + m]);
            wd1a1[mt] = pk(W1[2 * HID + m], B1[m]);
        }
    } else {
#pragma unroll
        for (int mt = 0; mt < 8; ++mt) { wd1a0[mt] = 0; wd1a1[mt] = 0; }
    }
    f16x8 wd2b[4];
    {
        const float* W2d = Wd2 + f * HID * 16;
#pragma unroll
        for (int s = 0; s < 4; ++s) {
            u32x4 v;
#pragma unroll
            for (int jp = 0; jp < 4; ++jp) {
                int k = quad * 8 + 32 * s + 2 * jp;
                v[jp] = pk(W2d[k * 16 + pt], W2d[(k + 1) * 16 + pt]);
            }
            wd2b[s] = __builtin_bit_cast(f16x8, v);
        }
    }
    const float bd2v = bd2[f * 16 + pt];
    const float c20 = bc2[f * 3 + 0], c21 = bc2[f * 3 + 1], c22 = bc2[f * 3 + 2];
    __syncthreads();

    const int tstart = tile * TILE;
#pragma unroll 1
    for (int it = 0; it < 8; ++it) {
        const int pbase = tstart + it * 64 + w * 16;
        if (pbase >= cnt) break;
        lfence();  // prior-iter reads ordered before staging overwrite

        // ---- staging: quad0 = pos/dir/idx; quad1/2 = app halves ----
        int plc = pbase + pt;
        if (plc > cnt - 1) plc = cnt - 1;
        const int idx = perm[start + plc];
        if (quad == 0) {
            sIdx[w][pt] = idx;
            float4 pv = make_float4(positions[idx * 3 + 0], positions[idx * 3 + 1],
                                    positions[idx * 3 + 2], 1.f);
            *(float4*)&sPos[w][pt * 4] = pv;
            u32x2 d2;
            d2.x = pk(directions[idx * 3 + 0], directions[idx * 3 + 1]);
            d2.y = pk(directions[idx * 3 + 2], 1.f);
            *(u32x2*)&sCin[w][pt * 72] = d2;
        } else if (quad == 1) {
            const float4* ap = (const float4*)(app + idx * 32);
            float4 a0 = ap[0], a1 = ap[1], a2 = ap[2], a3 = ap[3];
            u32x4 v0, v1;
            v0.x = pk(a0.x, a0.y); v0.y = pk(a0.z, a0.w);
            v0.z = pk(a1.x, a1.y); v0.w = pk(a1.z, a1.w);
            v1.x = pk(a2.x, a2.y); v1.y = pk(a2.z, a2.w);
            v1.z = pk(a3.x, a3.y); v1.w = pk(a3.z, a3.w);
            *(u32x4*)&sCin[w][pt * 72 + 8] = v0;
            *(u32x4*)&sCin[w][pt * 72 + 16] = v1;
        } else if (quad == 2) {
            const float4* ap = (const float4*)(app + idx * 32);
            float4 a0 = ap[4], a1 = ap[5], a2 = ap[6], a3 = ap[7];
            u32x4 v0, v1;
            v0.x = pk(a0.x, a0.y); v0.y = pk(a0.z, a0.w);
            v0.z = pk(a1.x, a1.y); v0.w = pk(a1.z, a1.w);
            v1.x = pk(a2.x, a2.y); v1.y = pk(a2.z, a2.w);
            v1.z = pk(a3.x, a3.y); v1.w = pk(a3.z, a3.w);
            *(u32x4*)&sCin[w][pt * 72 + 24] = v0;
            *(u32x4*)&sCin[w][pt * 72 + 32] = v1;
        }
        lfence();

        // ---- L1 transposed: h^T[128x16] = Wd1^T (A, resident) x X^T (B) ----
        float4 pv = *(float4*)&sPos[w][pt * 4];
        u32 x01 = (quad == 0) ? pk(pv.x, pv.y) : 0u;
        u32 x23 = (quad == 0) ? pk(pv.z, pv.w) : 0u;
        u32x4 xv; xv.x = x01; xv.y = x23; xv.z = 0u; xv.w = 0u;
        const f16x8 xb = __builtin_bit_cast(f16x8, xv);
#pragma unroll
        for (int mt = 0; mt < 8; ++mt) {
            u32x4 av; av.x = wd1a0[mt]; av.y = wd1a1[mt]; av.z = 0u; av.w = 0u;
            f16x8 af = __builtin_bit_cast(f16x8, av);
            f32x4 acc = {0.f, 0.f, 0.f, 0.f};
            acc = __builtin_amdgcn_mfma_f32_16x16x32_f16(af, xb, acc, 0, 0, 0);
            u32x2 hw;
            hw.x = pk(fmaxf(acc[0], 0.f), fmaxf(acc[1], 0.f));
            hw.y = pk(fmaxf(acc[2], 0.f), fmaxf(acc[3], 0.f));
            // C: col=pt, row=quad*4+reg -> H[pt][16mt+quad*4 ..+3]
            *(u32x2*)&sH[w][pt * 136 + 16 * mt + quad * 4] = hw;
        }
        lfence();

        // ---- L2: dout[16x16] = h (A from H) x Wd2 (B resident), bias in C ----
        f32x4 dacc = {bd2v, bd2v, bd2v, bd2v};
#pragma unroll
        for (int s = 0; s < 4; ++s) {
            f16x8 ha = __builtin_bit_cast(f16x8,
                *(const u32x4*)&sH[w][pt * 136 + quad * 8 + 32 * s]);
            dacc = __builtin_amdgcn_mfma_f32_16x16x32_f16(ha, wd2b[s], dacc, 0, 0, 0);
        }
        // C: col = o = pt, row = point = quad*4+reg
        if (pt == 0) {
            int4 si = *(const int4*)&sIdx[w][quad * 4];
            out[si.x * 4] = __expf(dacc[0]);
            out[si.y * 4] = __expf(dacc[1]);
            out[si.z * 4] = __expf(dacc[2]);
            out[si.w * 4] = __expf(dacc[3]);
        } else {
#pragma unroll
            for (int r = 0; r < 4; ++r)
                sCin[w][(quad * 4 + r) * 72 + 40 + (pt - 1)] = (f16)dacc[r];
        }
        lfence();

        // ---- L3 transposed (c1) + L4 (c2) fused per m-tile ----
        const f16x8 cb0 = __builtin_bit_cast(f16x8,
            *(const u32x4*)&sCin[w][pt * 72 + quad * 8]);
        const f16x8 cb1 = __builtin_bit_cast(f16x8,
            *(const u32x4*)&sCin[w][pt * 72 + quad * 8 + 32]);
        float r0 = 0.f, r1 = 0.f, r2 = 0.f;
#pragma unroll
        for (int mt = 0; mt < 8; ++mt) {
            f16x8 wa0 = __builtin_bit_cast(f16x8,
                *(const u32x4*)&sWc1t[(16 * mt + pt) * 72 + quad * 8]);
            f16x8 wa1 = __builtin_bit_cast(f16x8,
                *(const u32x4*)&sWc1t[(16 * mt + pt) * 72 + quad * 8 + 32]);
            f32x4 cacc = {0.f, 0.f, 0.f, 0.f};
            cacc = __builtin_amdgcn_mfma_f32_16x16x32_f16(wa0, cb0, cacc, 0, 0, 0);
            cacc = __builtin_amdgcn_mfma_f32_16x16x32_f16(wa1, cb1, cacc, 0, 0, 0);
            // lane holds hc[hid=16mt+quad*4+reg][pt]
            u32 h01 = pk(fmaxf(cacc[0], 0.f), fmaxf(cacc[1], 0.f));
            u32 h23 = pk(fmaxf(cacc[2], 0.f), fmaxf(cacc[3], 0.f));
            u32x4 w01 = *(const u32x4*)&sWc2p[(8 * mt + 2 * quad) * 4];
            u32x4 w23 = *(const u32x4*)&sWc2p[(8 * mt + 2 * quad + 1) * 4];
            r0 = dot2a(h01, w01.x, r0); r0 = dot2a(h23, w23.x, r0);
            r1 = dot2a(h01, w01.y, r1); r1 = dot2a(h23, w23.y, r1);
            r2 = dot2a(h01, w01.z, r2); r2 = dot2a(h23, w23.z, r2);
        }
        r0 += __shfl_xor(r0, 16, 64); r0 += __shfl_xor(r0, 32, 64);
        r1 += __shfl_xor(r1, 16, 64); r1 += __shfl_xor(r1, 32, 64);
        r2 += __shfl_xor(r2, 16, 64); r2 += __shfl_xor(r2, 32, 64);
        if (quad == 0) {  // this lane staged pt -> idx still in register
            float s0 = 1.f / (1.f + __expf(-(r0 + c20)));
            float s1 = 1.f / (1.f + __expf(-(r1 + c21)));
            float s2 = 1.f / (1.f + __expf(-(r2 + c22)));
            out[idx * 4 + 1] = s0;
            *(float2*)&out[idx * 4 + 2] = make_float2(s1, s2);
        }
    }
}

extern "C" void kernel_launch(void* const* d_in, const int* in_sizes, int n_in,
                              void* d_out, int out_size, void* d_ws, size_t ws_size,
                              hipStream_t stream) {
    const float* positions = (const float*)d_in[0];
    const float* directions = (const float*)d_in[1];
    const float* app = (const float*)d_in[2];
    const float* centroids = (const float*)d_in[3];
    const float* Wd1 = (const float*)d_in[4];
    const float* bd1 = (const float*)d_in[5];
    const float* Wd2 = (const float*)d_in[6];
    const float* bd2 = (const float*)d_in[7];
    const float* Wc1 = (const float*)d_in[8];
    const float* bc1 = (const float*)d_in[9];
    const float* Wc2 = (const float*)d_in[10];
    const float* bc2 = (const float*)d_in[11];
    float* out = (float*)d_out;
    int* wsi = (int*)d_ws;
    const int n = in_sizes[0] / 3;
    const int nb4 = (n + 1023) / 1024;
    const int max_tiles = (n + TILE - 1) / TILE + NF - 1;

    k_count<<<nb4, 256, 0, stream>>>(positions, centroids, n, wsi + 32);
    k_scan<<<1, 512, 0, stream>>>(wsi, nb4);
    k_scatter<<<nb4, 256, 0, stream>>>(positions, centroids, n, nb4, wsi);
    k_main<<<max_tiles, 256, 0, stream>>>(positions, directions, app, Wd1, bd1, Wd2,
                                          bd2, Wc1, bc1, Wc2, bc2, wsi, nb4, out);
}

// Round 8
// 175.006 us; speedup vs baseline: 21.8952x; 1.1410x over previous
//
#include <hip/hip_runtime.h>
#include <math.h>

#define NF 8
#define HID 128
#define TILE 768   // points per k_main block (4 waves x 12 iters x 16 pts)
#define NIT 12

typedef _Float16 f16;
typedef _Float16 h2 __attribute__((ext_vector_type(2)));
typedef _Float16 f16x8 __attribute__((ext_vector_type(8)));
typedef float f32x4 __attribute__((ext_vector_type(4)));
typedef unsigned int u32;
typedef u32 u32x2 __attribute__((ext_vector_type(2)));
typedef u32 u32x4 __attribute__((ext_vector_type(4)));

__device__ __forceinline__ u32 pk(float a, float b) {
    return __builtin_bit_cast(u32, __builtin_amdgcn_cvt_pkrtz(a, b));
}
__device__ __forceinline__ float dot2a(u32 a, u32 b, float c) {
    return __builtin_amdgcn_fdot2(__builtin_bit_cast(h2, a),
                                  __builtin_bit_cast(h2, b), c, false);
}
__device__ __forceinline__ void lfence() {
    asm volatile("s_waitcnt lgkmcnt(0)" ::: "memory");
}

// ws int layout:
//   [0..7] counts, [8..15] starts, [16..23] tile-prefix, [24] total tiles
//   [32 .. 32+NB*8) per-block counts;  [32+NB*8 ..) perm

__device__ __forceinline__ int assign_field(float px, float py, float pz,
                                            const float* __restrict__ cen) {
    int best = 0;
    float bd = 3.4e38f;
#pragma unroll
    for (int k = 0; k < NF; ++k) {
        float dx = px - cen[k * 3 + 0];
        float dy = py - cen[k * 3 + 1];
        float dz = pz - cen[k * 3 + 2];
        float d = fmaf(dx, dx, fmaf(dy, dy, dz * dz));
        if (d < bd) { bd = d; best = k; }
    }
    return best;
}

// 512 threads, 4 points per thread; per-block counts only (no global atomics).
__global__ void k_count(const float* __restrict__ pos, const float* __restrict__ cen,
                        int n, int* __restrict__ blockcnt) {
    __shared__ int lc[NF];
    int tid = threadIdx.x;
    if (tid < NF) lc[tid] = 0;
    __syncthreads();
    int i4 = blockIdx.x * blockDim.x + tid;
    int base = i4 * 4;
    if (base + 3 < n) {
        const float4* p4 = (const float4*)pos;
        float4 a = p4[i4 * 3 + 0];
        float4 b = p4[i4 * 3 + 1];
        float4 c = p4[i4 * 3 + 2];
        atomicAdd(&lc[assign_field(a.x, a.y, a.z, cen)], 1);
        atomicAdd(&lc[assign_field(a.w, b.x, b.y, cen)], 1);
        atomicAdd(&lc[assign_field(b.z, b.w, c.x, cen)], 1);
        atomicAdd(&lc[assign_field(c.y, c.z, c.w, cen)], 1);
    } else {
        for (int i = base; i < n; ++i)
            atomicAdd(&lc[assign_field(pos[3 * i], pos[3 * i + 1], pos[3 * i + 2], cen)], 1);
    }
    __syncthreads();
    if (tid < NF) blockcnt[blockIdx.x * NF + tid] = lc[tid];
}

// Fused scan+scatter: every block redundantly scans the (nb x 8) count table
// (2 KB from L2), derives its own write offsets, then scatters its 4-pt chunk.
// Block 0 also writes the ws header. 512 threads; wave f owns field f in scan.
__global__ void k_scatscan(const float* __restrict__ pos, const float* __restrict__ cen,
                           int n, int nb, int* __restrict__ ws) {
    const int tid = threadIdx.x;
    const int f = tid >> 6, lane = tid & 63;
    const int* c = ws + 32;
    int* perm = ws + 32 + nb * NF;
    __shared__ int totals[NF], pres[NF], starts[NF], cur[NF];

    int tot = 0, pre = 0;
    for (int b = lane; b < nb; b += 64) {
        int v = c[b * NF + f];
        tot += v;
        if (b < (int)blockIdx.x) pre += v;
    }
#pragma unroll
    for (int d = 1; d < 64; d <<= 1) {
        tot += __shfl_xor(tot, d, 64);
        pre += __shfl_xor(pre, d, 64);
    }
    if (lane == 0) { totals[f] = tot; pres[f] = pre; }
    __syncthreads();
    if (tid == 0) {
        int s = 0, tp = 0;
        for (int k = 0; k < NF; ++k) {
            starts[k] = s;
            if (blockIdx.x == 0) {
                ws[k] = totals[k];
                ws[8 + k] = s;
                ws[16 + k] = tp;
            }
            s += totals[k];
            tp += (totals[k] + TILE - 1) / TILE;
        }
        if (blockIdx.x == 0) ws[24] = tp;
    }
    __syncthreads();
    if (tid < NF) cur[tid] = starts[tid] + pres[tid];
    __syncthreads();

    int i4 = blockIdx.x * blockDim.x + tid;
    int base = i4 * 4;
    if (base + 3 < n) {
        const float4* p4 = (const float4*)pos;
        float4 a = p4[i4 * 3 + 0];
        float4 b = p4[i4 * 3 + 1];
        float4 cc = p4[i4 * 3 + 2];
        int f0 = assign_field(a.x, a.y, a.z, cen);
        int f1 = assign_field(a.w, b.x, b.y, cen);
        int f2 = assign_field(b.z, b.w, cc.x, cen);
        int f3 = assign_field(cc.y, cc.z, cc.w, cen);
        perm[atomicAdd(&cur[f0], 1)] = base;
        perm[atomicAdd(&cur[f1], 1)] = base + 1;
        perm[atomicAdd(&cur[f2], 1)] = base + 2;
        perm[atomicAdd(&cur[f3], 1)] = base + 3;
    } else {
        for (int i = base; i < n; ++i) {
            int ff = assign_field(pos[3 * i], pos[3 * i + 1], pos[3 * i + 2], cen);
            perm[atomicAdd(&cur[ff], 1)] = i;
        }
    }
}

// MFMA k_main with software prefetch of the per-point gather.
// cin layout per point (72 halves): [0..2]=dir, [3]=1(bias), [4..7]=0,
// [8..39]=app, [40..54]=geo, [55..63]=0. Wc1^T staged to match.
__global__ __launch_bounds__(256, 3) void k_main(
    const float* __restrict__ positions, const float* __restrict__ directions,
    const float* __restrict__ app,
    const float* __restrict__ Wd1, const float* __restrict__ bd1,
    const float* __restrict__ Wd2, const float* __restrict__ bd2,
    const float* __restrict__ Wc1, const float* __restrict__ bc1,
    const float* __restrict__ Wc2, const float* __restrict__ bc2,
    const int* __restrict__ ws, int nb, float* __restrict__ out) {
    const int b = blockIdx.x;
    if (b >= ws[24]) return;
    int f = 0;
#pragma unroll
    for (int k = 1; k < NF; ++k) if (b >= ws[16 + k]) f = k;
    const int tile = b - ws[16 + f];
    const int cnt = ws[f];
    const int start = ws[8 + f];
    const int* perm = ws + 32 + nb * NF;
    const int tid = threadIdx.x;
    const int w = tid >> 6, lane = tid & 63;
    const int pt = lane & 15, quad = lane >> 4;

    __shared__ __align__(16) f16 sWc1t[HID * 72];   // [h][72] permuted    18 KB
    __shared__ __align__(16) u32 sWc2p[64 * 4];     // [hp][ch] h2 pairs    1 KB
    __shared__ __align__(16) int sIdx[4][16];
    __shared__ __align__(16) f16 sCin[4][16 * 72];  // per-wave             9 KB
    __shared__ __align__(16) f16 sH[4][16 * 136];   // per-wave            17 KB

    // ---- stage Wc1^T (permuted, f16) and Wc2 pairs ----
    if (tid < HID) {
        int h = tid;
        f16* row = &sWc1t[h * 72];
        const float* Wf = Wc1 + f * 50 * HID;
        row[0] = (f16)Wf[0 * HID + h];
        row[1] = (f16)Wf[1 * HID + h];
        row[2] = (f16)Wf[2 * HID + h];
        row[3] = (f16)bc1[f * HID + h];
        row[4] = 0; row[5] = 0; row[6] = 0; row[7] = 0;
        for (int a = 0; a < 32; ++a) row[8 + a] = (f16)Wf[(18 + a) * HID + h];
        for (int g = 0; g < 15; ++g) row[40 + g] = (f16)Wf[(3 + g) * HID + h];
        for (int z = 55; z < 72; ++z) row[z] = 0;
    }
    if (tid < 64) {
        int hp = tid;
        const float* W2 = Wc2 + f * HID * 3;
        sWc2p[hp * 4 + 0] = pk(W2[(2 * hp) * 3 + 0], W2[(2 * hp + 1) * 3 + 0]);
        sWc2p[hp * 4 + 1] = pk(W2[(2 * hp) * 3 + 1], W2[(2 * hp + 1) * 3 + 1]);
        sWc2p[hp * 4 + 2] = pk(W2[(2 * hp) * 3 + 2], W2[(2 * hp + 1) * 3 + 2]);
        sWc2p[hp * 4 + 3] = 0;
    }
    if (lane < 16) {  // zero cin pad zones (per-wave region)
        f16* row = &sCin[w][pt * 72];
        u32x2 z2; z2.x = 0; z2.y = 0;
        *(u32x2*)&row[4] = z2;
        row[55] = 0;
        u32x4 z4; z4.x = 0; z4.y = 0; z4.z = 0; z4.w = 0;
        *(u32x4*)&row[56] = z4;
    }

    // ---- resident fragments (from global) ----
    u32 wd1a0[8], wd1a1[8];
    if (quad == 0) {
        const float* W1 = Wd1 + f * 3 * HID;
        const float* B1 = bd1 + f * HID;
#pragma unroll
        for (int mt = 0; mt < 8; ++mt) {
            int m = 16 * mt + pt;
            wd1a0[mt] = pk(W1[m], W1[HID + m]);
            wd1a1[mt] = pk(W1[2 * HID + m], B1[m]);
        }
    } else {
#pragma unroll
        for (int mt = 0; mt < 8; ++mt) { wd1a0[mt] = 0; wd1a1[mt] = 0; }
    }
    f16x8 wd2b[4];
    {
        const float* W2d = Wd2 + f * HID * 16;
#pragma unroll
        for (int s = 0; s < 4; ++s) {
            u32x4 v;
#pragma unroll
            for (int jp = 0; jp < 4; ++jp) {
                int k = quad * 8 + 32 * s + 2 * jp;
                v[jp] = pk(W2d[k * 16 + pt], W2d[(k + 1) * 16 + pt]);
            }
            wd2b[s] = __builtin_bit_cast(f16x8, v);
        }
    }
    const float bd2v = bd2[f * 16 + pt];
    const float c20 = bc2[f * 3 + 0], c21 = bc2[f * 3 + 1], c22 = bc2[f * 3 + 2];
    __syncthreads();

    const int tstart = tile * TILE;

    // ---- prefetch registers (iter's gather lives here one iter early) ----
    int g_idx;
    float4 g_p;                    // quad0: pos.xyz + 1
    float g_d0, g_d1, g_d2;        // quad0: dir
    float4 g_a0, g_a1, g_a2, g_a3; // quad1: app[0..15]; quad2: app[16..31]
    {
        int plc = tstart + w * 16 + pt;
        if (plc > cnt - 1) plc = cnt - 1;
        g_idx = perm[start + plc];
        if (quad == 0) {
            g_p = make_float4(positions[g_idx * 3 + 0], positions[g_idx * 3 + 1],
                              positions[g_idx * 3 + 2], 1.f);
            g_d0 = directions[g_idx * 3 + 0];
            g_d1 = directions[g_idx * 3 + 1];
            g_d2 = directions[g_idx * 3 + 2];
        } else if (quad < 3) {
            const float4* ap = (const float4*)(app + g_idx * 32) + (quad == 2 ? 4 : 0);
            g_a0 = ap[0]; g_a1 = ap[1]; g_a2 = ap[2]; g_a3 = ap[3];
        }
    }

#pragma unroll 1
    for (int it = 0; it < NIT; ++it) {
        const int pbase = tstart + it * 64 + w * 16;
        if (pbase >= cnt) break;
        lfence();  // prior-iter LDS reads done before staging overwrite

        // ---- stage prefetched gather into LDS ----
        const int cur_idx = g_idx;
        const float4 cur_p = g_p;
        if (quad == 0) {
            sIdx[w][pt] = g_idx;
            u32x2 d2;
            d2.x = pk(g_d0, g_d1);
            d2.y = pk(g_d2, 1.f);
            *(u32x2*)&sCin[w][pt * 72] = d2;
        } else if (quad == 1) {
            u32x4 v0, v1;
            v0.x = pk(g_a0.x, g_a0.y); v0.y = pk(g_a0.z, g_a0.w);
            v0.z = pk(g_a1.x, g_a1.y); v0.w = pk(g_a1.z, g_a1.w);
            v1.x = pk(g_a2.x, g_a2.y); v1.y = pk(g_a2.z, g_a2.w);
            v1.z = pk(g_a3.x, g_a3.y); v1.w = pk(g_a3.z, g_a3.w);
            *(u32x4*)&sCin[w][pt * 72 + 8] = v0;
            *(u32x4*)&sCin[w][pt * 72 + 16] = v1;
        } else if (quad == 2) {
            u32x4 v0, v1;
            v0.x = pk(g_a0.x, g_a0.y); v0.y = pk(g_a0.z, g_a0.w);
            v0.z = pk(g_a1.x, g_a1.y); v0.w = pk(g_a1.z, g_a1.w);
            v1.x = pk(g_a2.x, g_a2.y); v1.y = pk(g_a2.z, g_a2.w);
            v1.z = pk(g_a3.x, g_a3.y); v1.w = pk(g_a3.z, g_a3.w);
            *(u32x4*)&sCin[w][pt * 72 + 24] = v0;
            *(u32x4*)&sCin[w][pt * 72 + 32] = v1;
        }
        lfence();

        // ---- issue next iter's gather (overlaps with compute below) ----
        {
            const int nbase = tstart + (it + 1) * 64 + w * 16;
            if (it + 1 < NIT && nbase < cnt) {
                int plc = nbase + pt;
                if (plc > cnt - 1) plc = cnt - 1;
                g_idx = perm[start + plc];
                if (quad == 0) {
                    g_p = make_float4(positions[g_idx * 3 + 0], positions[g_idx * 3 + 1],
                                      positions[g_idx * 3 + 2], 1.f);
                    g_d0 = directions[g_idx * 3 + 0];
                    g_d1 = directions[g_idx * 3 + 1];
                    g_d2 = directions[g_idx * 3 + 2];
                } else if (quad < 3) {
                    const float4* ap = (const float4*)(app + g_idx * 32) + (quad == 2 ? 4 : 0);
                    g_a0 = ap[0]; g_a1 = ap[1]; g_a2 = ap[2]; g_a3 = ap[3];
                }
            }
        }

        // ---- L1 transposed: h^T[128x16] = Wd1^T (A resident) x X^T (B regs) ----
        u32 x01 = (quad == 0) ? pk(cur_p.x, cur_p.y) : 0u;
        u32 x23 = (quad == 0) ? pk(cur_p.z, cur_p.w) : 0u;
        u32x4 xv; xv.x = x01; xv.y = x23; xv.z = 0u; xv.w = 0u;
        const f16x8 xb = __builtin_bit_cast(f16x8, xv);
#pragma unroll
        for (int mt = 0; mt < 8; ++mt) {
            u32x4 av; av.x = wd1a0[mt]; av.y = wd1a1[mt]; av.z = 0u; av.w = 0u;
            f16x8 af = __builtin_bit_cast(f16x8, av);
            f32x4 acc = {0.f, 0.f, 0.f, 0.f};
            acc = __builtin_amdgcn_mfma_f32_16x16x32_f16(af, xb, acc, 0, 0, 0);
            u32x2 hw;
            hw.x = pk(fmaxf(acc[0], 0.f), fmaxf(acc[1], 0.f));
            hw.y = pk(fmaxf(acc[2], 0.f), fmaxf(acc[3], 0.f));
            // C: col=pt, row=quad*4+reg -> H[pt][16mt+quad*4 ..+3]
            *(u32x2*)&sH[w][pt * 136 + 16 * mt + quad * 4] = hw;
        }
        lfence();

        // ---- L2: dout[16x16] = h (A from H) x Wd2 (B resident), bias in C ----
        f32x4 dacc = {bd2v, bd2v, bd2v, bd2v};
#pragma unroll
        for (int s = 0; s < 4; ++s) {
            f16x8 ha = __builtin_bit_cast(f16x8,
                *(const u32x4*)&sH[w][pt * 136 + quad * 8 + 32 * s]);
            dacc = __builtin_amdgcn_mfma_f32_16x16x32_f16(ha, wd2b[s], dacc, 0, 0, 0);
        }
        // C: col = o = pt, row = point = quad*4+reg
        if (pt == 0) {
            int4 si = *(const int4*)&sIdx[w][quad * 4];
            out[si.x * 4] = __expf(dacc[0]);
            out[si.y * 4] = __expf(dacc[1]);
            out[si.z * 4] = __expf(dacc[2]);
            out[si.w * 4] = __expf(dacc[3]);
        } else {
#pragma unroll
            for (int r = 0; r < 4; ++r)
                sCin[w][(quad * 4 + r) * 72 + 40 + (pt - 1)] = (f16)dacc[r];
        }
        lfence();

        // ---- L3 transposed (c1) + L4 (c2) fused per m-tile ----
        const f16x8 cb0 = __builtin_bit_cast(f16x8,
            *(const u32x4*)&sCin[w][pt * 72 + quad * 8]);
        const f16x8 cb1 = __builtin_bit_cast(f16x8,
            *(const u32x4*)&sCin[w][pt * 72 + quad * 8 + 32]);
        float r0 = 0.f, r1 = 0.f, r2 = 0.f;
#pragma unroll
        for (int mt = 0; mt < 8; ++mt) {
            f16x8 wa0 = __builtin_bit_cast(f16x8,
                *(const u32x4*)&sWc1t[(16 * mt + pt) * 72 + quad * 8]);
            f16x8 wa1 = __builtin_bit_cast(f16x8,
                *(const u32x4*)&sWc1t[(16 * mt + pt) * 72 + quad * 8 + 32]);
            f32x4 cacc = {0.f, 0.f, 0.f, 0.f};
            cacc = __builtin_amdgcn_mfma_f32_16x16x32_f16(wa0, cb0, cacc, 0, 0, 0);
            cacc = __builtin_amdgcn_mfma_f32_16x16x32_f16(wa1, cb1, cacc, 0, 0, 0);
            // lane holds hc[hid=16mt+quad*4+reg][pt]
            u32 h01 = pk(fmaxf(cacc[0], 0.f), fmaxf(cacc[1], 0.f));
            u32 h23 = pk(fmaxf(cacc[2], 0.f), fmaxf(cacc[3], 0.f));
            u32x4 w01 = *(const u32x4*)&sWc2p[(8 * mt + 2 * quad) * 4];
            u32x4 w23 = *(const u32x4*)&sWc2p[(8 * mt + 2 * quad + 1) * 4];
            r0 = dot2a(h01, w01.x, r0); r0 = dot2a(h23, w23.x, r0);
            r1 = dot2a(h01, w01.y, r1); r1 = dot2a(h23, w23.y, r1);
            r2 = dot2a(h01, w01.z, r2); r2 = dot2a(h23, w23.z, r2);
        }
        r0 += __shfl_xor(r0, 16, 64); r0 += __shfl_xor(r0, 32, 64);
        r1 += __shfl_xor(r1, 16, 64); r1 += __shfl_xor(r1, 32, 64);
        r2 += __shfl_xor(r2, 16, 64); r2 += __shfl_xor(r2, 32, 64);
        if (quad == 0) {  // this lane staged pt -> cur_idx in register
            float s0 = 1.f / (1.f + __expf(-(r0 + c20)));
            float s1 = 1.f / (1.f + __expf(-(r1 + c21)));
            float s2 = 1.f / (1.f + __expf(-(r2 + c22)));
            out[cur_idx * 4 + 1] = s0;
            *(float2*)&out[cur_idx * 4 + 2] = make_float2(s1, s2);
        }
    }
}

extern "C" void kernel_launch(void* const* d_in, const int* in_sizes, int n_in,
                              void* d_out, int out_size, void* d_ws, size_t ws_size,
                              hipStream_t stream) {
    const float* positions = (const float*)d_in[0];
    const float* directions = (const float*)d_in[1];
    const float* app = (const float*)d_in[2];
    const float* centroids = (const float*)d_in[3];
    const float* Wd1 = (const float*)d_in[4];
    const float* bd1 = (const float*)d_in[5];
    const float* Wd2 = (const float*)d_in[6];
    const float* bd2 = (const float*)d_in[7];
    const float* Wc1 = (const float*)d_in[8];
    const float* bc1 = (const float*)d_in[9];
    const float* Wc2 = (const float*)d_in[10];
    const float* bc2 = (const float*)d_in[11];
    float* out = (float*)d_out;
    int* wsi = (int*)d_ws;
    const int n = in_sizes[0] / 3;
    const int nb = (n + 2047) / 2048;   // 512 threads x 4 pts
    const int max_tiles = (n + TILE - 1) / TILE + NF;

    k_count<<<nb, 512, 0, stream>>>(positions, centroids, n, wsi + 32);
    k_scatscan<<<nb, 512, 0, stream>>>(positions, centroids, n, nb, wsi);
    k_main<<<max_tiles, 256, 0, stream>>>(positions, directions, app, Wd1, bd1, Wd2,
                                          bd2, Wc1, bc1, Wc2, bc2, wsi, nb, out);
}